// Round 2
// baseline (1062.923 us; speedup 1.0000x reference)
//
#include <hip/hip_runtime.h>
#include <hip/hip_bf16.h>

// GCN 2-layer encoder, MI355X. Diagnostic/robust round:
//  - device-side dtype detection (fp32-vs-bf16 floats, int64-vs-int32 edges)
//  - canonicalize weights/edges; flag-branched loads for x and stores for out
//  - fused VALU MLP (a1 -> h1 in LDS -> h2), no MFMA this round (isolate)
// Pipeline: agg1(x) -> a1 ; mlp: h2s = (relu(a1@W1+b1)@W2)*dinv ; agg2 -> out

typedef short s16x8 __attribute__((ext_vector_type(8)));

#define IN_DIM 128
#define HID    256
#define OUTD   128

__device__ __forceinline__ float2 bf2f(__hip_bfloat162 v) {
    return make_float2(__bfloat162float(v.x), __bfloat162float(v.y));
}
__device__ __forceinline__ __hip_bfloat162 f2bf(float a, float b) {
    __hip_bfloat162 r; r.x = __float2bfloat16(a); r.y = __float2bfloat16(b); return r;
}

// ---------------- dtype detection ----------------
// flags[0] = 1 if float arrays are fp32 (else bf16)
// flags[1] = 1 if edge_index is int64 (else int32)
__global__ void k_detect(const void* W2raw, const void* eiraw, int* flags) {
    if (threadIdx.x != 0 || blockIdx.x != 0) return;
    const unsigned short* u = (const unsigned short*)W2raw;
    int f32 = 0;
    for (int i = 0; i < 64; ++i) {
        unsigned e = (u[i] >> 7) & 0xFF;          // bf16 exponent field
        if (e >= 0x7F) f32 = 1;                   // |W2| <= 1/16 -> exp <= 0x7A if bf16
    }
    const unsigned* ip = (const unsigned*)eiraw;
    unsigned orodd = 0;
    for (int i = 0; i < 64; ++i) orodd |= ip[2 * i + 1];  // int64 upper halves == 0
    flags[0] = f32;
    flags[1] = (orodd == 0) ? 1 : 0;
}

__global__ void k_canon_w(const void* src_, int n, const int* __restrict__ flags,
                          __hip_bfloat16* __restrict__ dst) {
    int i = blockIdx.x * 256 + threadIdx.x;
    if (i >= n) return;
    if (flags[0]) dst[i] = __float2bfloat16(((const float*)src_)[i]);
    else          dst[i] = ((const __hip_bfloat16*)src_)[i];
}

__global__ void k_canon_e(const void* ei_, int E, const int* __restrict__ flags,
                          int* __restrict__ srcv, int* __restrict__ dstv) {
    int i = blockIdx.x * 256 + threadIdx.x;
    if (i >= E) return;
    if (flags[1]) {
        const long long* p = (const long long*)ei_;
        srcv[i] = (int)p[i];
        dstv[i] = (int)p[E + i];
    } else {
        const int* p = (const int*)ei_;
        srcv[i] = p[i];
        dstv[i] = p[E + i];
    }
}

// ---------------- degree / CSR construction ----------------

__global__ void k_count(const int* __restrict__ dst, int E, int N, int* __restrict__ deg) {
    for (int e = blockIdx.x * blockDim.x + threadIdx.x; e < E; e += gridDim.x * blockDim.x) {
        int d = dst[e];
        if ((unsigned)d >= (unsigned)N) d = 0;    // defensive
        atomicAdd(&deg[d], 1);
    }
}

__global__ void k_block_sums(const int* __restrict__ deg, int* __restrict__ bsum, int n) {
    __shared__ int s[256];
    int i = blockIdx.x * 256 + threadIdx.x;
    s[threadIdx.x] = (i < n) ? deg[i] : 0;
    __syncthreads();
    for (int off = 128; off > 0; off >>= 1) {
        if (threadIdx.x < off) s[threadIdx.x] += s[threadIdx.x + off];
        __syncthreads();
    }
    if (threadIdx.x == 0) bsum[blockIdx.x] = s[0];
}

__global__ void k_spine(const int* __restrict__ bsum, int* __restrict__ boff, int nb) {
    __shared__ int s[256];
    int t = threadIdx.x;
    int v = (t < nb) ? bsum[t] : 0;
    s[t] = v; __syncthreads();
    for (int off = 1; off < 256; off <<= 1) {
        int u = (t >= off) ? s[t - off] : 0;
        __syncthreads();
        s[t] += u;
        __syncthreads();
    }
    if (t < nb) boff[t] = s[t] - v;   // exclusive
}

__global__ void k_scan_final(const int* __restrict__ deg, const int* __restrict__ boff,
                             int* __restrict__ offsets, int* __restrict__ cursor, int n) {
    __shared__ int s[256];
    int t = threadIdx.x;
    int i = blockIdx.x * 256 + t;
    int v = (i < n) ? deg[i] : 0;
    s[t] = v; __syncthreads();
    for (int off = 1; off < 256; off <<= 1) {
        int u = (t >= off) ? s[t - off] : 0;
        __syncthreads();
        s[t] += u;
        __syncthreads();
    }
    int excl = boff[blockIdx.x] + s[t] - v;
    if (i < n) {
        offsets[i] = excl;
        cursor[i]  = excl;
        if (i == n - 1) offsets[n] = excl + v;
    }
}

__global__ void k_dinv(const int* __restrict__ deg, float* __restrict__ dinv, int n, int npad) {
    int i = blockIdx.x * 256 + threadIdx.x;
    if (i < npad) {
        int d = (i < n) ? deg[i] : -1;
        dinv[i] = (i < n) ? rsqrtf((float)(d > 0 ? d + 1 : 1)) : 0.f;   // +1 self-loop
    }
}

__global__ void k_fill(const int* __restrict__ src, const int* __restrict__ dst, int E, int N,
                       int* __restrict__ cursor, int* __restrict__ csr) {
    for (int e = blockIdx.x * blockDim.x + threadIdx.x; e < E; e += gridDim.x * blockDim.x) {
        int d = dst[e], s = src[e];
        if ((unsigned)d >= (unsigned)N) d = 0;    // defensive
        if ((unsigned)s >= (unsigned)N) s = 0;
        int p = atomicAdd(&cursor[d], 1);
        csr[p] = s;
    }
}

// ---------------- aggregation 1: a1 = Dinv (A+I) Dinv x  (128 feats) ----------------

__global__ __launch_bounds__(256) void k_agg1(
        const void* __restrict__ xraw, const int* __restrict__ offsets,
        const int* __restrict__ csr, const float* __restrict__ dinv,
        const int* __restrict__ flags,
        __hip_bfloat16* __restrict__ a1, int N, int Npad, int nwaves) {
    int gw   = blockIdx.x * 4 + (threadIdx.x >> 6);
    int lane = threadIdx.x & 63;
    int f32  = flags[0];                                   // wave-uniform
    const float2*          xf = (const float2*)xraw;       // 128 floats = 64 float2 per row
    const __hip_bfloat162* xb = (const __hip_bfloat162*)xraw;
    __hip_bfloat162* a2 = (__hip_bfloat162*)a1;
    for (int v = gw; v < Npad; v += nwaves) {
        if (v >= N) { a2[(size_t)v * 64 + lane] = f2bf(0.f, 0.f); continue; }
        float dv = dinv[v];
        float2 xs = f32 ? xf[(size_t)v * 64 + lane] : bf2f(xb[(size_t)v * 64 + lane]);
        float ax = dv * xs.x, ay = dv * xs.y;              // self-loop term
        int o0 = offsets[v], o1 = offsets[v + 1];
        for (int e = o0; e < o1; ++e) {
            int s = csr[e];
            if ((unsigned)s >= (unsigned)N) s = 0;         // defensive
            float ds = dinv[s];
            float2 t = f32 ? xf[(size_t)s * 64 + lane] : bf2f(xb[(size_t)s * 64 + lane]);
            ax += ds * t.x; ay += ds * t.y;
        }
        a2[(size_t)v * 64 + lane] = f2bf(dv * ax, dv * ay);
    }
}

// ---------------- fused MLP: h2s[r,:] = dinv[r] * (relu(a1[r,:]@W1 + b1) @ W2) ----------------

__global__ __launch_bounds__(256) void k_mlp(
        const __hip_bfloat16* __restrict__ a1, const __hip_bfloat16* __restrict__ W1c,
        const __hip_bfloat16* __restrict__ b1c, const __hip_bfloat16* __restrict__ W2c,
        const float* __restrict__ dinv, __hip_bfloat16* __restrict__ h2s) {
    __shared__ __align__(16) __hip_bfloat16 At[64 * IN_DIM];   // 16 KB
    __shared__ __align__(16) __hip_bfloat16 H1[64 * HID];      // 32 KB
    int t  = threadIdx.x;
    int r0 = blockIdx.x * 64;

    // stage A tile (64 x 128 bf16) coalesced
    const s16x8* Ag = (const s16x8*)(a1 + (size_t)r0 * IN_DIM);
    s16x8* Al = (s16x8*)At;
    for (int i = t; i < 64 * IN_DIM / 8; i += 256) Al[i] = Ag[i];
    __syncthreads();

    // phase A: each thread owns column t of H1, loops 64 rows
    {
        float bv = __bfloat162float(b1c[t]);
        for (int row = 0; row < 64; ++row) {
            const __hip_bfloat162* Ar = (const __hip_bfloat162*)(At + row * IN_DIM);
            float acc = 0.f;
#pragma unroll 8
            for (int k2 = 0; k2 < IN_DIM / 2; ++k2) {
                float2 a = bf2f(Ar[k2]);
                acc += a.x * __bfloat162float(W1c[(2 * k2)     * HID + t]);
                acc += a.y * __bfloat162float(W1c[(2 * k2 + 1) * HID + t]);
            }
            float v = acc + bv;
            H1[row * HID + t] = __float2bfloat16(v > 0.f ? v : 0.f);
        }
    }
    __syncthreads();

    // phase B: col = t&127, two row-groups, 32 rows each
    {
        int col = t & 127, rh = t >> 7;
        for (int row = rh; row < 64; row += 2) {
            const __hip_bfloat162* Hr = (const __hip_bfloat162*)(H1 + row * HID);
            float acc = 0.f;
#pragma unroll 8
            for (int k2 = 0; k2 < HID / 2; ++k2) {
                float2 h = bf2f(Hr[k2]);
                acc += h.x * __bfloat162float(W2c[(2 * k2)     * OUTD + col]);
                acc += h.y * __bfloat162float(W2c[(2 * k2 + 1) * OUTD + col]);
            }
            int gr = r0 + row;
            h2s[(size_t)gr * OUTD + col] = __float2bfloat16(acc * dinv[gr]);
        }
    }
}

// ---------------- aggregation 2: out = Dinv (A+I) h2s + b2  (128 feats) ----------------

__global__ __launch_bounds__(256) void k_agg2(
        const __hip_bfloat16* __restrict__ h2, const int* __restrict__ offsets,
        const int* __restrict__ csr, const float* __restrict__ dinv,
        const __hip_bfloat16* __restrict__ b2c, const int* __restrict__ flags,
        void* __restrict__ outraw, int N, int nwaves) {
    int gw   = blockIdx.x * 4 + (threadIdx.x >> 6);
    int lane = threadIdx.x & 63;
    int f32  = flags[0];
    const __hip_bfloat162* h22 = (const __hip_bfloat162*)h2;
    float2 bb = bf2f(((const __hip_bfloat162*)b2c)[lane]);
    for (int v = gw; v < N; v += nwaves) {
        float2 a = bf2f(h22[(size_t)v * 64 + lane]);       // self (rows pre-scaled by dinv)
        float ax = a.x, ay = a.y;
        int o0 = offsets[v], o1 = offsets[v + 1];
        for (int e = o0; e < o1; ++e) {
            int s = csr[e];
            if ((unsigned)s >= (unsigned)N) s = 0;         // defensive
            float2 t = bf2f(h22[(size_t)s * 64 + lane]);
            ax += t.x; ay += t.y;
        }
        float dv = dinv[v];
        float ox = dv * ax + bb.x, oy = dv * ay + bb.y;
        if (f32) ((float2*)outraw)[(size_t)v * 64 + lane] = make_float2(ox, oy);
        else     ((__hip_bfloat162*)outraw)[(size_t)v * 64 + lane] = f2bf(ox, oy);
    }
}

// ---------------- host launch ----------------

extern "C" void kernel_launch(void* const* d_in, const int* in_sizes, int n_in,
                              void* d_out, int out_size, void* d_ws, size_t ws_size,
                              hipStream_t stream) {
    const void* x  = d_in[0];
    const void* ei = d_in[1];
    const void* W1 = d_in[2];
    const void* b1 = d_in[3];
    const void* W2 = d_in[4];
    const void* b2 = d_in[5];

    const int N = in_sizes[0] / IN_DIM;       // 50000
    const int E = in_sizes[1] / 2;            // 800000
    const int Npad = ((N + 63) / 64) * 64;    // 50048

    char* w = (char*)d_ws;
    auto alloc = [&](size_t bytes) -> void* {
        void* p = (void*)w;
        w += (bytes + 255) / 256 * 256;
        return p;
    };
    int*   flags   = (int*)alloc(256);
    int*   deg     = (int*)alloc((size_t)Npad * 4);
    int*   offsets = (int*)alloc((size_t)(N + 1) * 4);
    int*   cursor  = (int*)alloc((size_t)N * 4);
    int*   bsum    = (int*)alloc(1024);
    int*   boff    = (int*)alloc(1024);
    float* dinv    = (float*)alloc((size_t)Npad * 4);
    int*   srcv    = (int*)alloc((size_t)E * 4);
    int*   dstv    = (int*)alloc((size_t)E * 4);
    int*   csr     = (int*)alloc((size_t)E * 4);
    __hip_bfloat16* W1c = (__hip_bfloat16*)alloc((size_t)IN_DIM * HID * 2);
    __hip_bfloat16* b1c = (__hip_bfloat16*)alloc((size_t)HID * 2);
    __hip_bfloat16* W2c = (__hip_bfloat16*)alloc((size_t)HID * OUTD * 2);
    __hip_bfloat16* b2c = (__hip_bfloat16*)alloc((size_t)OUTD * 2);
    __hip_bfloat16* a1  = (__hip_bfloat16*)alloc((size_t)Npad * IN_DIM * 2);
    __hip_bfloat16* h2s = (__hip_bfloat16*)alloc((size_t)Npad * OUTD * 2);

    k_detect<<<1, 64, 0, stream>>>(W2, ei, flags);

    k_canon_w<<<(IN_DIM * HID + 255) / 256, 256, 0, stream>>>(W1, IN_DIM * HID, flags, W1c);
    k_canon_w<<<1, 256, 0, stream>>>(b1, HID, flags, b1c);
    k_canon_w<<<(HID * OUTD + 255) / 256, 256, 0, stream>>>(W2, HID * OUTD, flags, W2c);
    k_canon_w<<<1, 256, 0, stream>>>(b2, OUTD, flags, b2c);
    k_canon_e<<<(E + 255) / 256, 256, 0, stream>>>(ei, E, flags, srcv, dstv);

    hipMemsetAsync(deg, 0, (size_t)Npad * 4, stream);
    k_count<<<640, 256, 0, stream>>>(dstv, E, N, deg);

    const int nb = (N + 255) / 256;           // 196
    k_block_sums<<<nb, 256, 0, stream>>>(deg, bsum, N);
    k_spine<<<1, 256, 0, stream>>>(bsum, boff, nb);
    k_scan_final<<<nb, 256, 0, stream>>>(deg, boff, offsets, cursor, N);
    k_dinv<<<(Npad + 255) / 256, 256, 0, stream>>>(deg, dinv, N, Npad);
    k_fill<<<640, 256, 0, stream>>>(srcv, dstv, E, N, cursor, csr);

    const int aggBlocks = 784, nwaves = aggBlocks * 4;
    k_agg1<<<aggBlocks, 256, 0, stream>>>(x, offsets, csr, dinv, flags, a1, N, Npad, nwaves);

    k_mlp<<<Npad / 64, 256, 0, stream>>>(a1, W1c, b1c, W2c, dinv, h2s);

    k_agg2<<<aggBlocks, 256, 0, stream>>>(h2s, offsets, csr, dinv, b2c, flags,
                                          d_out, N, nwaves);
}

// Round 3
// 322.953 us; speedup vs baseline: 3.2913x; 3.2913x over previous
//
#include <hip/hip_runtime.h>
#include <hip/hip_bf16.h>

// GCN 2-layer encoder, MI355X (gfx950).
// Established round 2: float tensors are bf16 (flags[0]==0), edge_index is
// int64 (flags[1]==1) — detection kept for robustness.
// Pipeline:
//   canon weights/edges -> CSR build -> dinv
//   xs = dinv * x (bf16 rows)                       [elementwise]
//   a1[v] = dinv[v] * (xs[v] + sum_{s->v} xs[s])    [gather, 128 feats]
//   h1 = relu(a1 @ W1 + b1)                          [MFMA GEMM]
//   h2s = (h1 @ W2) * dinv[row]                      [MFMA GEMM]
//   out[v] = dinv[v]*(h2s[v] + sum h2s[s]) + b2      [gather, 128 feats]

typedef __bf16 bf16x8v __attribute__((ext_vector_type(8)));
typedef short  s16x8   __attribute__((ext_vector_type(8)));
typedef float  f32x4   __attribute__((ext_vector_type(4)));

#define IN_DIM 128
#define HID    256
#define OUTD   128

__device__ __forceinline__ float2 bf2f(__hip_bfloat162 v) {
    return make_float2(__bfloat162float(v.x), __bfloat162float(v.y));
}
__device__ __forceinline__ __hip_bfloat162 f2bf(float a, float b) {
    __hip_bfloat162 r; r.x = __float2bfloat16(a); r.y = __float2bfloat16(b); return r;
}

// ---------------- dtype detection ----------------
__global__ void k_detect(const void* W2raw, const void* eiraw, int* flags) {
    if (threadIdx.x != 0 || blockIdx.x != 0) return;
    const unsigned short* u = (const unsigned short*)W2raw;
    int f32 = 0;
    for (int i = 0; i < 64; ++i) {
        unsigned e = (u[i] >> 7) & 0xFF;
        if (e >= 0x7F) f32 = 1;          // |W2|<=1/16 => bf16 exp <= 0x7A
    }
    const unsigned* ip = (const unsigned*)eiraw;
    unsigned orodd = 0;
    for (int i = 0; i < 64; ++i) orodd |= ip[2 * i + 1];
    flags[0] = f32;
    flags[1] = (orodd == 0) ? 1 : 0;     // int64 upper words all zero
}

__global__ void k_canon_w(const void* src_, int n, const int* __restrict__ flags,
                          __hip_bfloat16* __restrict__ dst) {
    int i = blockIdx.x * 256 + threadIdx.x;
    if (i >= n) return;
    if (flags[0]) dst[i] = __float2bfloat16(((const float*)src_)[i]);
    else          dst[i] = ((const __hip_bfloat16*)src_)[i];
}

__global__ void k_canon_e(const void* ei_, int E, const int* __restrict__ flags,
                          int* __restrict__ srcv, int* __restrict__ dstv) {
    int i = blockIdx.x * 256 + threadIdx.x;
    if (i >= E) return;
    if (flags[1]) {
        const long long* p = (const long long*)ei_;
        srcv[i] = (int)p[i];
        dstv[i] = (int)p[E + i];
    } else {
        const int* p = (const int*)ei_;
        srcv[i] = p[i];
        dstv[i] = p[E + i];
    }
}

// ---------------- degree / CSR ----------------

__global__ void k_count(const int* __restrict__ dst, int E, int N, int* __restrict__ deg) {
    for (int e = blockIdx.x * blockDim.x + threadIdx.x; e < E; e += gridDim.x * blockDim.x) {
        int d = dst[e];
        if ((unsigned)d >= (unsigned)N) d = 0;
        atomicAdd(&deg[d], 1);
    }
}

__global__ void k_block_sums(const int* __restrict__ deg, int* __restrict__ bsum, int n) {
    __shared__ int s[256];
    int i = blockIdx.x * 256 + threadIdx.x;
    s[threadIdx.x] = (i < n) ? deg[i] : 0;
    __syncthreads();
    for (int off = 128; off > 0; off >>= 1) {
        if (threadIdx.x < off) s[threadIdx.x] += s[threadIdx.x + off];
        __syncthreads();
    }
    if (threadIdx.x == 0) bsum[blockIdx.x] = s[0];
}

__global__ void k_spine(const int* __restrict__ bsum, int* __restrict__ boff, int nb) {
    __shared__ int s[256];
    int t = threadIdx.x;
    int v = (t < nb) ? bsum[t] : 0;
    s[t] = v; __syncthreads();
    for (int off = 1; off < 256; off <<= 1) {
        int u = (t >= off) ? s[t - off] : 0;
        __syncthreads();
        s[t] += u;
        __syncthreads();
    }
    if (t < nb) boff[t] = s[t] - v;
}

__global__ void k_scan_final(const int* __restrict__ deg, const int* __restrict__ boff,
                             int* __restrict__ offsets, int* __restrict__ cursor, int n) {
    __shared__ int s[256];
    int t = threadIdx.x;
    int i = blockIdx.x * 256 + t;
    int v = (i < n) ? deg[i] : 0;
    s[t] = v; __syncthreads();
    for (int off = 1; off < 256; off <<= 1) {
        int u = (t >= off) ? s[t - off] : 0;
        __syncthreads();
        s[t] += u;
        __syncthreads();
    }
    int excl = boff[blockIdx.x] + s[t] - v;
    if (i < n) {
        offsets[i] = excl;
        cursor[i]  = excl;
        if (i == n - 1) offsets[n] = excl + v;
    }
}

__global__ void k_dinv(const int* __restrict__ deg, float* __restrict__ dinv, int n, int npad) {
    int i = blockIdx.x * 256 + threadIdx.x;
    if (i < npad) dinv[i] = (i < n) ? rsqrtf((float)(deg[i] + 1)) : 0.f;
}

__global__ void k_fill(const int* __restrict__ src, const int* __restrict__ dst, int E, int N,
                       int* __restrict__ cursor, int* __restrict__ csr) {
    for (int e = blockIdx.x * blockDim.x + threadIdx.x; e < E; e += gridDim.x * blockDim.x) {
        int d = dst[e], s = src[e];
        if ((unsigned)d >= (unsigned)N) d = 0;
        if ((unsigned)s >= (unsigned)N) s = 0;
        int p = atomicAdd(&cursor[d], 1);
        csr[p] = s;
    }
}

// ---------------- xs = dinv * x  (bf16 rows, pad rows zeroed) ----------------

__global__ __launch_bounds__(256) void k_prescale_x(
        const void* __restrict__ xraw, const float* __restrict__ dinv,
        const int* __restrict__ flags, __hip_bfloat162* __restrict__ xs2,
        int N, int Npad) {
    int gid = blockIdx.x * 256 + threadIdx.x;
    int v = gid >> 6, lane = gid & 63;
    if (v >= Npad) return;
    __hip_bfloat162 val;
    if (v < N) {
        float dv = dinv[v];
        float2 t = flags[0] ? ((const float2*)xraw)[(size_t)v * 64 + lane]
                            : bf2f(((const __hip_bfloat162*)xraw)[(size_t)v * 64 + lane]);
        val = f2bf(dv * t.x, dv * t.y);
    } else val = f2bf(0.f, 0.f);
    xs2[(size_t)v * 64 + lane] = val;
}

// ---------------- weight swizzle into MFMA B-fragment order ----------------
// Bsw[(nt*KC+kc)*64 + lane][j] = W[kc*32 + (lane>>4)*8 + j][nt*16 + (lane&15)]

template <int K, int NN>
__global__ void k_swz(const short* __restrict__ W, short* __restrict__ Bsw) {
    constexpr int KC = K / 32;
    constexpr int NT = NN / 16;
    int tid = blockIdx.x * blockDim.x + threadIdx.x;
    if (tid >= NT * KC * 64) return;
    int lane = tid & 63;
    int kc   = (tid >> 6) % KC;
    int nt   = tid / (64 * KC);
    int n  = nt * 16 + (lane & 15);
    int kb = kc * 32 + (lane >> 4) * 8;
    s16x8 v;
#pragma unroll
    for (int j = 0; j < 8; ++j) v[j] = W[(kb + j) * NN + n];
    ((s16x8*)Bsw)[tid] = v;
}

// ---------------- aggregation 1: a1[v] = dv*(xs[v] + sum xs[csr]) ----------------

__global__ __launch_bounds__(256) void k_agg1(
        const __hip_bfloat162* __restrict__ xs2, const int* __restrict__ offsets,
        const int* __restrict__ csr, const float* __restrict__ dinv,
        __hip_bfloat162* __restrict__ a2, int N, int Npad, int nwaves) {
    int gw   = blockIdx.x * 4 + (threadIdx.x >> 6);
    int lane = threadIdx.x & 63;
    for (int v = gw; v < Npad; v += nwaves) {
        if (v >= N) { a2[(size_t)v * 64 + lane] = f2bf(0.f, 0.f); continue; }
        float2 s0v = bf2f(xs2[(size_t)v * 64 + lane]);
        float ax = s0v.x, ay = s0v.y;
        int e = offsets[v], o1 = offsets[v + 1];
        for (; e + 3 < o1; e += 4) {
            int s0 = csr[e], s1 = csr[e + 1], s2 = csr[e + 2], s3 = csr[e + 3];
            float2 t0 = bf2f(xs2[(size_t)s0 * 64 + lane]);
            float2 t1 = bf2f(xs2[(size_t)s1 * 64 + lane]);
            float2 t2 = bf2f(xs2[(size_t)s2 * 64 + lane]);
            float2 t3 = bf2f(xs2[(size_t)s3 * 64 + lane]);
            ax += (t0.x + t1.x) + (t2.x + t3.x);
            ay += (t0.y + t1.y) + (t2.y + t3.y);
        }
        for (; e < o1; ++e) {
            int s = csr[e];
            float2 t = bf2f(xs2[(size_t)s * 64 + lane]);
            ax += t.x; ay += t.y;
        }
        float dv = dinv[v];
        a2[(size_t)v * 64 + lane] = f2bf(dv * ax, dv * ay);
    }
}

// ---------------- MFMA GEMM: C[M,NN] = A[M,K] @ W[K,NN] (+epilogue) ----------------
// Block = 4 waves; wave owns 16 rows, loops NN/16 col-tiles; A-frags in regs,
// B from pre-swizzled global table (L2-hot).

template <int K, int NN, bool RELU_BIAS>
__global__ __launch_bounds__(256) void k_gemm(
        const __hip_bfloat16* __restrict__ A, const __hip_bfloat16* __restrict__ Bsw,
        const __hip_bfloat16* __restrict__ bias, const float* __restrict__ dinv,
        __hip_bfloat16* __restrict__ C) {
    constexpr int KC = K / 32;
    constexpr int NT = NN / 16;
    int wave = threadIdx.x >> 6, lane = threadIdx.x & 63;
    int quad = lane >> 4, l16 = lane & 15;
    int m0 = blockIdx.x * 64 + wave * 16;

    bf16x8v a[KC];
#pragma unroll
    for (int kc = 0; kc < KC; ++kc)
        a[kc] = *reinterpret_cast<const bf16x8v*>(A + (size_t)(m0 + l16) * K + kc * 32 + quad * 8);

    const bf16x8v* B8 = reinterpret_cast<const bf16x8v*>(Bsw);
    int rowbase = m0 + quad * 4;
    float scale[4];
    if (!RELU_BIAS) {
#pragma unroll
        for (int r = 0; r < 4; ++r) scale[r] = dinv[rowbase + r];
    }

    for (int nt = 0; nt < NT; ++nt) {
        f32x4 acc = {0.f, 0.f, 0.f, 0.f};
#pragma unroll
        for (int kc = 0; kc < KC; ++kc)
            acc = __builtin_amdgcn_mfma_f32_16x16x32_bf16(a[kc], B8[(nt * KC + kc) * 64 + lane], acc, 0, 0, 0);
        int col = nt * 16 + l16;
        if (RELU_BIAS) {
            float bv = __bfloat162float(bias[col]);
#pragma unroll
            for (int r = 0; r < 4; ++r) {
                float v = acc[r] + bv;
                v = v > 0.f ? v : 0.f;
                C[(size_t)(rowbase + r) * NN + col] = __float2bfloat16(v);
            }
        } else {
#pragma unroll
            for (int r = 0; r < 4; ++r)
                C[(size_t)(rowbase + r) * NN + col] = __float2bfloat16(acc[r] * scale[r]);
        }
    }
}

// ---------------- aggregation 2: out[v] = dv*(h2s[v] + sum h2s[csr]) + b2 ----------------

__global__ __launch_bounds__(256) void k_agg2(
        const __hip_bfloat162* __restrict__ h22, const int* __restrict__ offsets,
        const int* __restrict__ csr, const float* __restrict__ dinv,
        const __hip_bfloat16* __restrict__ b2c, const int* __restrict__ flags,
        void* __restrict__ outraw, int N, int nwaves) {
    int gw   = blockIdx.x * 4 + (threadIdx.x >> 6);
    int lane = threadIdx.x & 63;
    int f32  = flags[0];
    float2 bb = bf2f(((const __hip_bfloat162*)b2c)[lane]);
    for (int v = gw; v < N; v += nwaves) {
        float2 a = bf2f(h22[(size_t)v * 64 + lane]);
        float ax = a.x, ay = a.y;
        int e = offsets[v], o1 = offsets[v + 1];
        for (; e + 3 < o1; e += 4) {
            int s0 = csr[e], s1 = csr[e + 1], s2 = csr[e + 2], s3 = csr[e + 3];
            float2 t0 = bf2f(h22[(size_t)s0 * 64 + lane]);
            float2 t1 = bf2f(h22[(size_t)s1 * 64 + lane]);
            float2 t2 = bf2f(h22[(size_t)s2 * 64 + lane]);
            float2 t3 = bf2f(h22[(size_t)s3 * 64 + lane]);
            ax += (t0.x + t1.x) + (t2.x + t3.x);
            ay += (t0.y + t1.y) + (t2.y + t3.y);
        }
        for (; e < o1; ++e) {
            int s = csr[e];
            float2 t = bf2f(h22[(size_t)s * 64 + lane]);
            ax += t.x; ay += t.y;
        }
        float dv = dinv[v];
        float ox = dv * ax + bb.x, oy = dv * ay + bb.y;
        if (f32) ((float2*)outraw)[(size_t)v * 64 + lane] = make_float2(ox, oy);
        else     ((__hip_bfloat162*)outraw)[(size_t)v * 64 + lane] = f2bf(ox, oy);
    }
}

// ---------------- host launch ----------------

extern "C" void kernel_launch(void* const* d_in, const int* in_sizes, int n_in,
                              void* d_out, int out_size, void* d_ws, size_t ws_size,
                              hipStream_t stream) {
    const void* x  = d_in[0];
    const void* ei = d_in[1];
    const void* W1 = d_in[2];
    const void* b1 = d_in[3];
    const void* W2 = d_in[4];
    const void* b2 = d_in[5];

    const int N = in_sizes[0] / IN_DIM;       // 50000
    const int E = in_sizes[1] / 2;            // 800000
    const int Npad = ((N + 63) / 64) * 64;    // 50048

    char* w = (char*)d_ws;
    auto alloc = [&](size_t bytes) -> void* {
        void* p = (void*)w;
        w += (bytes + 255) / 256 * 256;
        return p;
    };
    int*   flags   = (int*)alloc(256);
    int*   deg     = (int*)alloc((size_t)Npad * 4);
    int*   offsets = (int*)alloc((size_t)(N + 1) * 4);
    int*   cursor  = (int*)alloc((size_t)N * 4);
    int*   bsum    = (int*)alloc(1024);
    int*   boff    = (int*)alloc(1024);
    float* dinv    = (float*)alloc((size_t)Npad * 4);
    int*   srcv    = (int*)alloc((size_t)E * 4);
    int*   dstv    = (int*)alloc((size_t)E * 4);
    int*   csr     = (int*)alloc((size_t)E * 4);
    __hip_bfloat16* W1c = (__hip_bfloat16*)alloc((size_t)IN_DIM * HID * 2);
    __hip_bfloat16* b1c = (__hip_bfloat16*)alloc((size_t)HID * 2);
    __hip_bfloat16* W2c = (__hip_bfloat16*)alloc((size_t)HID * OUTD * 2);
    __hip_bfloat16* b2c = (__hip_bfloat16*)alloc((size_t)OUTD * 2);
    short* Bsw1 = (short*)alloc((size_t)IN_DIM * HID * 2);
    short* Bsw2 = (short*)alloc((size_t)HID * OUTD * 2);
    __hip_bfloat16* xs  = (__hip_bfloat16*)alloc((size_t)Npad * IN_DIM * 2);
    __hip_bfloat16* a1  = (__hip_bfloat16*)alloc((size_t)Npad * IN_DIM * 2);
    __hip_bfloat16* h1  = (__hip_bfloat16*)alloc((size_t)Npad * HID * 2);
    __hip_bfloat16* h2s = xs;   // xs dead after agg1; reuse for GEMM2 output

    k_detect<<<1, 64, 0, stream>>>(W2, ei, flags);

    k_canon_w<<<(IN_DIM * HID + 255) / 256, 256, 0, stream>>>(W1, IN_DIM * HID, flags, W1c);
    k_canon_w<<<1, 256, 0, stream>>>(b1, HID, flags, b1c);
    k_canon_w<<<(HID * OUTD + 255) / 256, 256, 0, stream>>>(W2, HID * OUTD, flags, W2c);
    k_canon_w<<<1, 256, 0, stream>>>(b2, OUTD, flags, b2c);
    k_canon_e<<<(E + 255) / 256, 256, 0, stream>>>(ei, E, flags, srcv, dstv);

    hipMemsetAsync(deg, 0, (size_t)Npad * 4, stream);
    k_count<<<640, 256, 0, stream>>>(dstv, E, N, deg);

    const int nb = (N + 255) / 256;           // 196
    k_block_sums<<<nb, 256, 0, stream>>>(deg, bsum, N);
    k_spine<<<1, 256, 0, stream>>>(bsum, boff, nb);
    k_scan_final<<<nb, 256, 0, stream>>>(deg, boff, offsets, cursor, N);
    k_dinv<<<(Npad + 255) / 256, 256, 0, stream>>>(deg, dinv, N, Npad);
    k_fill<<<640, 256, 0, stream>>>(srcv, dstv, E, N, cursor, csr);

    k_prescale_x<<<(Npad * 64 + 255) / 256, 256, 0, stream>>>(x, dinv, flags,
                                                              (__hip_bfloat162*)xs, N, Npad);

    k_swz<IN_DIM, HID><<<16, 256, 0, stream>>>((const short*)W1c, Bsw1);
    k_swz<HID, OUTD><<<16, 256, 0, stream>>>((const short*)W2c, Bsw2);

    const int aggBlocks = 2048, nwaves = aggBlocks * 4;
    k_agg1<<<aggBlocks, 256, 0, stream>>>((const __hip_bfloat162*)xs, offsets, csr, dinv,
                                          (__hip_bfloat162*)a1, N, Npad, nwaves);

    k_gemm<IN_DIM, HID, true><<<Npad / 64, 256, 0, stream>>>(
        a1, (const __hip_bfloat16*)Bsw1, b1c, nullptr, h1);
    k_gemm<HID, OUTD, false><<<Npad / 64, 256, 0, stream>>>(
        h1, (const __hip_bfloat16*)Bsw2, nullptr, dinv, h2s);

    k_agg2<<<aggBlocks, 256, 0, stream>>>((const __hip_bfloat162*)h2s, offsets, csr, dinv,
                                          b2c, flags, d_out, N, nwaves);
}

// Round 4
// 284.189 us; speedup vs baseline: 3.7402x; 1.1364x over previous
//
#include <hip/hip_runtime.h>
#include <hip/hip_bf16.h>

// GCN 2-layer encoder, MI355X (gfx950).
// Known from rounds 2-3: float tensors are bf16, edge_index is int64
// (detection kept, ~0 cost). Round 4: replace atomic-cursor CSR build
// (k_count+k_fill, ~100us, 53MB scattered-line writebacks) with a bucketed
// build: coarse histogram -> scan -> partition (line-local writes) ->
// per-bucket LDS counting sort (coalesced CSR + offsets + dinv).
// Pipeline:
//   canon weights/edges -> bucket CSR build -> dinv
//   xs = dinv * x (bf16 rows)
//   a1[v] = dinv[v] * (xs[v] + sum_{s->v} xs[s])     [gather]
//   h1 = relu(a1 @ W1 + b1)                           [MFMA]
//   h2s = (h1 @ W2) * dinv[row]                       [MFMA]
//   out[v] = dinv[v]*(h2s[v] + sum h2s[s]) + b2       [gather]

typedef __bf16 bf16x8v __attribute__((ext_vector_type(8)));
typedef short  s16x8   __attribute__((ext_vector_type(8)));
typedef float  f32x4   __attribute__((ext_vector_type(4)));

#define IN_DIM 128
#define HID    256
#define OUTD   128
#define BKT_SHIFT 7
#define BKT_NODES 128
#define MAXB 512            // max buckets supported (N <= 65536)

__device__ __forceinline__ float2 bf2f(__hip_bfloat162 v) {
    return make_float2(__bfloat162float(v.x), __bfloat162float(v.y));
}
__device__ __forceinline__ __hip_bfloat162 f2bf(float a, float b) {
    __hip_bfloat162 r; r.x = __float2bfloat16(a); r.y = __float2bfloat16(b); return r;
}

// ---------------- dtype detection ----------------
__global__ void k_detect(const void* W2raw, const void* eiraw, int* flags) {
    if (threadIdx.x != 0 || blockIdx.x != 0) return;
    const unsigned short* u = (const unsigned short*)W2raw;
    int f32 = 0;
    for (int i = 0; i < 64; ++i) {
        unsigned e = (u[i] >> 7) & 0xFF;
        if (e >= 0x7F) f32 = 1;          // |W2|<=1/16 => bf16 exp <= 0x7A
    }
    const unsigned* ip = (const unsigned*)eiraw;
    unsigned orodd = 0;
    for (int i = 0; i < 64; ++i) orodd |= ip[2 * i + 1];
    flags[0] = f32;
    flags[1] = (orodd == 0) ? 1 : 0;     // int64 upper words all zero
}

__global__ void k_canon_w(const void* src_, int n, const int* __restrict__ flags,
                          __hip_bfloat16* __restrict__ dst) {
    int i = blockIdx.x * 256 + threadIdx.x;
    if (i >= n) return;
    if (flags[0]) dst[i] = __float2bfloat16(((const float*)src_)[i]);
    else          dst[i] = ((const __hip_bfloat16*)src_)[i];
}

__global__ void k_canon_e(const void* ei_, int E, int N, const int* __restrict__ flags,
                          int* __restrict__ srcv, int* __restrict__ dstv) {
    int i = blockIdx.x * 256 + threadIdx.x;
    if (i >= E) return;
    int s, d;
    if (flags[1]) {
        const long long* p = (const long long*)ei_;
        s = (int)p[i]; d = (int)p[E + i];
    } else {
        const int* p = (const int*)ei_;
        s = p[i]; d = p[E + i];
    }
    if ((unsigned)s >= (unsigned)N) s = 0;
    if ((unsigned)d >= (unsigned)N) d = 0;
    srcv[i] = s; dstv[i] = d;
}

// ---------------- bucketed CSR build ----------------

__global__ __launch_bounds__(256) void k_bhist(const int* __restrict__ dstv, int E, int NB,
                                               int* __restrict__ bhist) {
    __shared__ int h[MAXB];
    for (int i = threadIdx.x; i < NB; i += 256) h[i] = 0;
    __syncthreads();
    for (int e = blockIdx.x * blockDim.x + threadIdx.x; e < E; e += gridDim.x * blockDim.x)
        atomicAdd(&h[((unsigned)dstv[e]) >> BKT_SHIFT], 1);
    __syncthreads();
    for (int i = threadIdx.x; i < NB; i += 256)
        if (h[i]) atomicAdd(&bhist[i], h[i]);
}

__global__ __launch_bounds__(512) void k_bscan(const int* __restrict__ bhist, int NB, int E,
                                               int* __restrict__ boff, int* __restrict__ gcur,
                                               int* __restrict__ offsets, float* __restrict__ dinv,
                                               int N, int Npad) {
    __shared__ int s[MAXB];
    int t = threadIdx.x;
    int v = (t < NB) ? bhist[t] : 0;
    s[t] = v; __syncthreads();
    for (int off = 1; off < MAXB; off <<= 1) {
        int u = (t >= off) ? s[t - off] : 0;
        __syncthreads();
        s[t] += u;
        __syncthreads();
    }
    if (t < NB) { boff[t] = s[t] - v; gcur[t] = s[t] - v; }
    if (t == 0) { boff[NB] = E; offsets[N] = E; }
    if (t < Npad - N) dinv[N + t] = 0.f;      // pad rows
}

__global__ __launch_bounds__(256) void k_part(const int* __restrict__ srcv,
                                              const int* __restrict__ dstv, int E, int NB,
                                              int* __restrict__ gcur, int* __restrict__ psrc,
                                              unsigned short* __restrict__ pldst) {
    __shared__ int base[MAXB], lcur[MAXB];
    int per = (E + gridDim.x - 1) / gridDim.x;
    int e0 = blockIdx.x * per, e1 = min(e0 + per, E);
    for (int i = threadIdx.x; i < NB; i += 256) lcur[i] = 0;
    __syncthreads();
    for (int e = e0 + threadIdx.x; e < e1; e += 256)
        atomicAdd(&lcur[((unsigned)dstv[e]) >> BKT_SHIFT], 1);
    __syncthreads();
    for (int i = threadIdx.x; i < NB; i += 256) {
        int c = lcur[i];
        base[i] = c ? atomicAdd(&gcur[i], c) : 0;
        lcur[i] = 0;
    }
    __syncthreads();
    for (int e = e0 + threadIdx.x; e < e1; e += 256) {
        int d = dstv[e];
        int b = ((unsigned)d) >> BKT_SHIFT;
        int pos = base[b] + atomicAdd(&lcur[b], 1);
        psrc[pos]  = srcv[e];
        pldst[pos] = (unsigned short)(d & (BKT_NODES - 1));
    }
}

// one block per bucket: counting-sort edges by local dst -> csr (coalesced
// 8KB window), write offsets + dinv for the bucket's 128 nodes.
__global__ __launch_bounds__(256) void k_bsort(const int* __restrict__ boff,
                                               const int* __restrict__ psrc,
                                               const unsigned short* __restrict__ pldst,
                                               int* __restrict__ csr, int* __restrict__ offsets,
                                               float* __restrict__ dinv, int N) {
    __shared__ int h[BKT_NODES], base[BKT_NODES], s[BKT_NODES];
    int b = blockIdx.x;
    int ebase = boff[b], eend = boff[b + 1];
    int t = threadIdx.x;
    if (t < BKT_NODES) h[t] = 0;
    __syncthreads();
    for (int e = ebase + t; e < eend; e += 256) atomicAdd(&h[pldst[e]], 1);
    __syncthreads();
    int v = (t < BKT_NODES) ? h[t] : 0;
    if (t < BKT_NODES) s[t] = v;
    __syncthreads();
    for (int off = 1; off < BKT_NODES; off <<= 1) {
        int u = (t < BKT_NODES && t >= off) ? s[t - off] : 0;
        __syncthreads();
        if (t < BKT_NODES) s[t] += u;
        __syncthreads();
    }
    if (t < BKT_NODES) {
        int excl = s[t] - v;
        base[t] = excl;
        int node = b * BKT_NODES + t;
        if (node < N) {
            offsets[node] = ebase + excl;
            dinv[node] = rsqrtf((float)(v + 1));
        }
        h[t] = 0;   // reuse as running cursor
    }
    __syncthreads();
    for (int e = ebase + t; e < eend; e += 256) {
        int ld = pldst[e];
        int pos = ebase + base[ld] + atomicAdd(&h[ld], 1);
        csr[pos] = psrc[e];
    }
}

// ---------------- xs = dinv * x  (bf16 rows, pad rows zeroed) ----------------

__global__ __launch_bounds__(256) void k_prescale_x(
        const void* __restrict__ xraw, const float* __restrict__ dinv,
        const int* __restrict__ flags, __hip_bfloat162* __restrict__ xs2,
        int N, int Npad) {
    int gid = blockIdx.x * 256 + threadIdx.x;
    int v = gid >> 6, lane = gid & 63;
    if (v >= Npad) return;
    __hip_bfloat162 val;
    if (v < N) {
        float dv = dinv[v];
        float2 t = flags[0] ? ((const float2*)xraw)[(size_t)v * 64 + lane]
                            : bf2f(((const __hip_bfloat162*)xraw)[(size_t)v * 64 + lane]);
        val = f2bf(dv * t.x, dv * t.y);
    } else val = f2bf(0.f, 0.f);
    xs2[(size_t)v * 64 + lane] = val;
}

// ---------------- weight swizzle into MFMA B-fragment order ----------------
// Bsw[(nt*KC+kc)*64 + lane][j] = W[kc*32 + (lane>>4)*8 + j][nt*16 + (lane&15)]

template <int K, int NN>
__global__ void k_swz(const short* __restrict__ W, short* __restrict__ Bsw) {
    constexpr int KC = K / 32;
    constexpr int NT = NN / 16;
    int tid = blockIdx.x * blockDim.x + threadIdx.x;
    if (tid >= NT * KC * 64) return;
    int lane = tid & 63;
    int kc   = (tid >> 6) % KC;
    int nt   = tid / (64 * KC);
    int n  = nt * 16 + (lane & 15);
    int kb = kc * 32 + (lane >> 4) * 8;
    s16x8 v;
#pragma unroll
    for (int j = 0; j < 8; ++j) v[j] = W[(kb + j) * NN + n];
    ((s16x8*)Bsw)[tid] = v;
}

// ---------------- aggregation 1: a1[v] = dv*(xs[v] + sum xs[csr]) ----------------

__global__ __launch_bounds__(256) void k_agg1(
        const __hip_bfloat162* __restrict__ xs2, const int* __restrict__ offsets,
        const int* __restrict__ csr, const float* __restrict__ dinv,
        __hip_bfloat162* __restrict__ a2, int N, int Npad, int nwaves) {
    int gw   = blockIdx.x * 4 + (threadIdx.x >> 6);
    int lane = threadIdx.x & 63;
    for (int v = gw; v < Npad; v += nwaves) {
        if (v >= N) { a2[(size_t)v * 64 + lane] = f2bf(0.f, 0.f); continue; }
        float2 s0v = bf2f(xs2[(size_t)v * 64 + lane]);
        float ax = s0v.x, ay = s0v.y;
        int e = offsets[v], o1 = offsets[v + 1];
        for (; e + 3 < o1; e += 4) {
            int s0 = csr[e], s1 = csr[e + 1], s2 = csr[e + 2], s3 = csr[e + 3];
            float2 t0 = bf2f(xs2[(size_t)s0 * 64 + lane]);
            float2 t1 = bf2f(xs2[(size_t)s1 * 64 + lane]);
            float2 t2 = bf2f(xs2[(size_t)s2 * 64 + lane]);
            float2 t3 = bf2f(xs2[(size_t)s3 * 64 + lane]);
            ax += (t0.x + t1.x) + (t2.x + t3.x);
            ay += (t0.y + t1.y) + (t2.y + t3.y);
        }
        for (; e < o1; ++e) {
            int s = csr[e];
            float2 t = bf2f(xs2[(size_t)s * 64 + lane]);
            ax += t.x; ay += t.y;
        }
        float dv = dinv[v];
        a2[(size_t)v * 64 + lane] = f2bf(dv * ax, dv * ay);
    }
}

// ---------------- MFMA GEMM: C[M,NN] = A[M,K] @ W[K,NN] (+epilogue) ----------------

template <int K, int NN, bool RELU_BIAS>
__global__ __launch_bounds__(256) void k_gemm(
        const __hip_bfloat16* __restrict__ A, const __hip_bfloat16* __restrict__ Bsw,
        const __hip_bfloat16* __restrict__ bias, const float* __restrict__ dinv,
        __hip_bfloat16* __restrict__ C) {
    constexpr int KC = K / 32;
    constexpr int NT = NN / 16;
    int wave = threadIdx.x >> 6, lane = threadIdx.x & 63;
    int quad = lane >> 4, l16 = lane & 15;
    int m0 = blockIdx.x * 64 + wave * 16;

    bf16x8v a[KC];
#pragma unroll
    for (int kc = 0; kc < KC; ++kc)
        a[kc] = *reinterpret_cast<const bf16x8v*>(A + (size_t)(m0 + l16) * K + kc * 32 + quad * 8);

    const bf16x8v* B8 = reinterpret_cast<const bf16x8v*>(Bsw);
    int rowbase = m0 + quad * 4;
    float scale[4];
    if (!RELU_BIAS) {
#pragma unroll
        for (int r = 0; r < 4; ++r) scale[r] = dinv[rowbase + r];
    }

    for (int nt = 0; nt < NT; ++nt) {
        f32x4 acc = {0.f, 0.f, 0.f, 0.f};
#pragma unroll
        for (int kc = 0; kc < KC; ++kc)
            acc = __builtin_amdgcn_mfma_f32_16x16x32_bf16(a[kc], B8[(nt * KC + kc) * 64 + lane], acc, 0, 0, 0);
        int col = nt * 16 + l16;
        if (RELU_BIAS) {
            float bv = __bfloat162float(bias[col]);
#pragma unroll
            for (int r = 0; r < 4; ++r) {
                float v = acc[r] + bv;
                v = v > 0.f ? v : 0.f;
                C[(size_t)(rowbase + r) * NN + col] = __float2bfloat16(v);
            }
        } else {
#pragma unroll
            for (int r = 0; r < 4; ++r)
                C[(size_t)(rowbase + r) * NN + col] = __float2bfloat16(acc[r] * scale[r]);
        }
    }
}

// ---------------- aggregation 2: out[v] = dv*(h2s[v] + sum h2s[csr]) + b2 ----------------

__global__ __launch_bounds__(256) void k_agg2(
        const __hip_bfloat162* __restrict__ h22, const int* __restrict__ offsets,
        const int* __restrict__ csr, const float* __restrict__ dinv,
        const __hip_bfloat16* __restrict__ b2c, const int* __restrict__ flags,
        void* __restrict__ outraw, int N, int nwaves) {
    int gw   = blockIdx.x * 4 + (threadIdx.x >> 6);
    int lane = threadIdx.x & 63;
    int f32  = flags[0];
    float2 bb = bf2f(((const __hip_bfloat162*)b2c)[lane]);
    for (int v = gw; v < N; v += nwaves) {
        float2 a = bf2f(h22[(size_t)v * 64 + lane]);
        float ax = a.x, ay = a.y;
        int e = offsets[v], o1 = offsets[v + 1];
        for (; e + 3 < o1; e += 4) {
            int s0 = csr[e], s1 = csr[e + 1], s2 = csr[e + 2], s3 = csr[e + 3];
            float2 t0 = bf2f(h22[(size_t)s0 * 64 + lane]);
            float2 t1 = bf2f(h22[(size_t)s1 * 64 + lane]);
            float2 t2 = bf2f(h22[(size_t)s2 * 64 + lane]);
            float2 t3 = bf2f(h22[(size_t)s3 * 64 + lane]);
            ax += (t0.x + t1.x) + (t2.x + t3.x);
            ay += (t0.y + t1.y) + (t2.y + t3.y);
        }
        for (; e < o1; ++e) {
            int s = csr[e];
            float2 t = bf2f(h22[(size_t)s * 64 + lane]);
            ax += t.x; ay += t.y;
        }
        float dv = dinv[v];
        float ox = dv * ax + bb.x, oy = dv * ay + bb.y;
        if (f32) ((float2*)outraw)[(size_t)v * 64 + lane] = make_float2(ox, oy);
        else     ((__hip_bfloat162*)outraw)[(size_t)v * 64 + lane] = f2bf(ox, oy);
    }
}

// ---------------- host launch ----------------

extern "C" void kernel_launch(void* const* d_in, const int* in_sizes, int n_in,
                              void* d_out, int out_size, void* d_ws, size_t ws_size,
                              hipStream_t stream) {
    const void* x  = d_in[0];
    const void* ei = d_in[1];
    const void* W1 = d_in[2];
    const void* b1 = d_in[3];
    const void* W2 = d_in[4];
    const void* b2 = d_in[5];

    const int N = in_sizes[0] / IN_DIM;       // 50000
    const int E = in_sizes[1] / 2;            // 800000
    const int Npad = ((N + 63) / 64) * 64;    // 50048
    const int NB = (N + BKT_NODES - 1) / BKT_NODES;   // 391

    char* w = (char*)d_ws;
    auto alloc = [&](size_t bytes) -> void* {
        void* p = (void*)w;
        w += (bytes + 255) / 256 * 256;
        return p;
    };
    int*   flags   = (int*)alloc(256);
    int*   offsets = (int*)alloc((size_t)(N + 1) * 4);
    float* dinv    = (float*)alloc((size_t)Npad * 4);
    int*   bhist   = (int*)alloc((size_t)MAXB * 4);
    int*   boff    = (int*)alloc((size_t)(MAXB + 1) * 4);
    int*   gcur    = (int*)alloc((size_t)MAXB * 4);
    int*   srcv    = (int*)alloc((size_t)E * 4);
    int*   dstv    = (int*)alloc((size_t)E * 4);
    int*   psrc    = (int*)alloc((size_t)E * 4);
    unsigned short* pldst = (unsigned short*)alloc((size_t)E * 2);
    int*   csr     = (int*)alloc((size_t)E * 4);
    __hip_bfloat16* W1c = (__hip_bfloat16*)alloc((size_t)IN_DIM * HID * 2);
    __hip_bfloat16* b1c = (__hip_bfloat16*)alloc((size_t)HID * 2);
    __hip_bfloat16* W2c = (__hip_bfloat16*)alloc((size_t)HID * OUTD * 2);
    __hip_bfloat16* b2c = (__hip_bfloat16*)alloc((size_t)OUTD * 2);
    short* Bsw1 = (short*)alloc((size_t)IN_DIM * HID * 2);
    short* Bsw2 = (short*)alloc((size_t)HID * OUTD * 2);
    __hip_bfloat16* xs  = (__hip_bfloat16*)alloc((size_t)Npad * IN_DIM * 2);
    __hip_bfloat16* a1  = (__hip_bfloat16*)alloc((size_t)Npad * IN_DIM * 2);
    __hip_bfloat16* h1  = (__hip_bfloat16*)alloc((size_t)Npad * HID * 2);
    __hip_bfloat16* h2s = xs;   // xs dead after agg1; reuse for GEMM2 output

    k_detect<<<1, 64, 0, stream>>>(W2, ei, flags);

    k_canon_w<<<(IN_DIM * HID + 255) / 256, 256, 0, stream>>>(W1, IN_DIM * HID, flags, W1c);
    k_canon_w<<<1, 256, 0, stream>>>(b1, HID, flags, b1c);
    k_canon_w<<<(HID * OUTD + 255) / 256, 256, 0, stream>>>(W2, HID * OUTD, flags, W2c);
    k_canon_w<<<1, 256, 0, stream>>>(b2, OUTD, flags, b2c);
    k_canon_e<<<(E + 255) / 256, 256, 0, stream>>>(ei, E, N, flags, srcv, dstv);

    hipMemsetAsync(bhist, 0, (size_t)MAXB * 4, stream);
    k_bhist<<<64, 256, 0, stream>>>(dstv, E, NB, bhist);
    k_bscan<<<1, MAXB, 0, stream>>>(bhist, NB, E, boff, gcur, offsets, dinv, N, Npad);
    k_part<<<64, 256, 0, stream>>>(srcv, dstv, E, NB, gcur, psrc, pldst);
    k_bsort<<<NB, 256, 0, stream>>>(boff, psrc, pldst, csr, offsets, dinv, N);

    k_prescale_x<<<(Npad * 64 + 255) / 256, 256, 0, stream>>>(x, dinv, flags,
                                                              (__hip_bfloat162*)xs, N, Npad);

    k_swz<IN_DIM, HID><<<16, 256, 0, stream>>>((const short*)W1c, Bsw1);
    k_swz<HID, OUTD><<<16, 256, 0, stream>>>((const short*)W2c, Bsw2);

    const int aggBlocks = 2048, nwaves = aggBlocks * 4;
    k_agg1<<<aggBlocks, 256, 0, stream>>>((const __hip_bfloat162*)xs, offsets, csr, dinv,
                                          (__hip_bfloat162*)a1, N, Npad, nwaves);

    k_gemm<IN_DIM, HID, true><<<Npad / 64, 256, 0, stream>>>(
        a1, (const __hip_bfloat16*)Bsw1, b1c, nullptr, h1);
    k_gemm<HID, OUTD, false><<<Npad / 64, 256, 0, stream>>>(
        h1, (const __hip_bfloat16*)Bsw2, nullptr, dinv, h2s);

    k_agg2<<<aggBlocks, 256, 0, stream>>>((const __hip_bfloat162*)h2s, offsets, csr, dinv,
                                          b2c, flags, d_out, N, nwaves);
}

// Round 5
// 252.880 us; speedup vs baseline: 4.2033x; 1.1238x over previous
//
#include <hip/hip_runtime.h>
#include <hip/hip_bf16.h>

// GCN 2-layer encoder, MI355X (gfx950).
// Known: float tensors are bf16, edge_index int64 (detection kept, ~0 cost).
// Round 5: collapse edge preprocessing to ONE pass (k_edges: direct int64
// read -> LDS hist -> per-bucket range reserve -> packed (ldst|src) scatter
// into fixed-cap buckets), fuse all weight prep into one kernel, GEMM waves
// own 32 rows (B-frag loads amortized over 2 A sets). 10 dispatches total.
// Pipeline:
//   k_prep_w: Bsw1/Bsw2 (MFMA B-frag order) + b1c/b2c, inline dtype canon
//   k_edges -> k_bscan -> k_bsort : bucketed CSR + offsets + dinv
//   xs = dinv * x
//   a1[v] = dinv[v]*(xs[v] + sum xs[csr])     [gather]
//   h1 = relu(a1 @ W1 + b1)                    [MFMA]
//   h2s = (h1 @ W2) * dinv[row]                [MFMA]
//   out[v] = dinv[v]*(h2s[v] + sum h2s[csr]) + b2

typedef __bf16 bf16x8v __attribute__((ext_vector_type(8)));
typedef short  s16x8   __attribute__((ext_vector_type(8)));
typedef float  f32x4   __attribute__((ext_vector_type(4)));

#define IN_DIM 128
#define HID    256
#define OUTD   128
#define BKT_SHIFT 7
#define BKT_NODES 128
#define MAXB 512            // max buckets (N <= 65536)
#define CAP  8192           // per-bucket capacity (mean 2046, 40+ sigma margin)

__device__ __forceinline__ float2 bf2f(__hip_bfloat162 v) {
    return make_float2(__bfloat162float(v.x), __bfloat162float(v.y));
}
__device__ __forceinline__ __hip_bfloat162 f2bf(float a, float b) {
    __hip_bfloat162 r; r.x = __float2bfloat16(a); r.y = __float2bfloat16(b); return r;
}

// ---------------- dtype detection ----------------
__global__ void k_detect(const void* W2raw, const void* eiraw, int* flags) {
    if (threadIdx.x != 0 || blockIdx.x != 0) return;
    const unsigned short* u = (const unsigned short*)W2raw;
    int f32 = 0;
    for (int i = 0; i < 64; ++i) {
        unsigned e = (u[i] >> 7) & 0xFF;
        if (e >= 0x7F) f32 = 1;          // |W2|<=1/16 => bf16 exp <= 0x7A
    }
    const unsigned* ip = (const unsigned*)eiraw;
    unsigned orodd = 0;
    for (int i = 0; i < 64; ++i) orodd |= ip[2 * i + 1];
    flags[0] = f32;
    flags[1] = (orodd == 0) ? 1 : 0;     // int64 upper words all zero
}

// ---------------- fused weight prep ----------------
// Bsw[(nt*KC+kc)*64 + lane][j] = W[kc*32 + (lane>>4)*8 + j][nt*16 + (lane&15)]

__device__ __forceinline__ short ldw(const void* raw, int idx, int f32) {
    if (f32) {
        __hip_bfloat16 h = __float2bfloat16(((const float*)raw)[idx]);
        return *(short*)&h;
    }
    return ((const short*)raw)[idx];
}

template <int K, int NN>
__device__ __forceinline__ void swz_one(const void* Wraw, int f32,
                                        short* __restrict__ Bsw, int tid) {
    constexpr int KC = K / 32;
    constexpr int NT = NN / 16;
    if (tid >= NT * KC * 64) return;
    int lane = tid & 63;
    int kc   = (tid >> 6) % KC;
    int nt   = tid / (64 * KC);
    int n  = nt * 16 + (lane & 15);
    int kb = kc * 32 + (lane >> 4) * 8;
    s16x8 v;
#pragma unroll
    for (int j = 0; j < 8; ++j) v[j] = ldw(Wraw, (kb + j) * NN + n, f32);
    ((s16x8*)Bsw)[tid] = v;
}

__global__ __launch_bounds__(256) void k_prep_w(
        const void* W1raw, const void* b1raw, const void* W2raw, const void* b2raw,
        const int* __restrict__ flags, short* __restrict__ Bsw1, short* __restrict__ Bsw2,
        __hip_bfloat16* __restrict__ b1c, __hip_bfloat16* __restrict__ b2c) {
    int f32 = flags[0];
    int blk = blockIdx.x, t = threadIdx.x;
    if (blk < 16) {                       // W1: 128x256 -> 4096 frag-lanes
        swz_one<IN_DIM, HID>(W1raw, f32, Bsw1, blk * 256 + t);
    } else if (blk < 32) {                // W2: 256x128 -> 4096 frag-lanes
        swz_one<HID, OUTD>(W2raw, f32, Bsw2, (blk - 16) * 256 + t);
    } else {                              // biases
        short s1 = ldw(b1raw, t, f32);
        b1c[t] = *(__hip_bfloat16*)&s1;
        if (t < OUTD) {
            short s2 = ldw(b2raw, t, f32);
            b2c[t] = *(__hip_bfloat16*)&s2;
        }
    }
}

// ---------------- one-pass edge bucketing ----------------
// Reads raw edge_index (int64 or int32). Packs (ldst<<25)|src per edge into
// fixed-capacity bucket regions ppack[b*CAP ..]. bcnt[b] = bucket count.

__global__ __launch_bounds__(256) void k_edges(
        const void* __restrict__ ei_, int E, int N, int NB,
        const int* __restrict__ flags, int* __restrict__ bcnt,
        unsigned* __restrict__ ppack) {
    __shared__ int lhist[MAXB], lbase[MAXB];
    int i64 = flags[1];
    const long long* p64 = (const long long*)ei_;
    const int*       p32 = (const int*)ei_;
    int per = (E + gridDim.x - 1) / gridDim.x;
    int e0 = blockIdx.x * per, e1 = min(e0 + per, E);
    for (int i = threadIdx.x; i < NB; i += 256) lhist[i] = 0;
    __syncthreads();
    for (int e = e0 + threadIdx.x; e < e1; e += 256) {
        int d = i64 ? (int)p64[E + e] : p32[E + e];
        if ((unsigned)d >= (unsigned)N) d = 0;
        atomicAdd(&lhist[((unsigned)d) >> BKT_SHIFT], 1);
    }
    __syncthreads();
    for (int i = threadIdx.x; i < NB; i += 256) {
        int c = lhist[i];
        lbase[i] = c ? atomicAdd(&bcnt[i], c) : 0;
        lhist[i] = 0;
    }
    __syncthreads();
    for (int e = e0 + threadIdx.x; e < e1; e += 256) {
        int d = i64 ? (int)p64[E + e] : p32[E + e];
        int s = i64 ? (int)p64[e]     : p32[e];
        if ((unsigned)d >= (unsigned)N) d = 0;
        if ((unsigned)s >= (unsigned)N) s = 0;
        int b = ((unsigned)d) >> BKT_SHIFT;
        int pos = lbase[b] + atomicAdd(&lhist[b], 1);
        if (pos < CAP)
            ppack[(size_t)b * CAP + pos] = ((unsigned)(d & (BKT_NODES - 1)) << 25) | (unsigned)s;
    }
}

__global__ __launch_bounds__(512) void k_bscan(int* __restrict__ bcnt, int NB,
                                               int* __restrict__ boff,
                                               int* __restrict__ offsets, float* __restrict__ dinv,
                                               int N, int Npad) {
    __shared__ int s[MAXB];
    int t = threadIdx.x;
    int c = (t < NB) ? min(bcnt[t], CAP) : 0;
    if (t < NB) bcnt[t] = c;             // clamp (overflow never expected)
    s[t] = c; __syncthreads();
    for (int off = 1; off < MAXB; off <<= 1) {
        int u = (t >= off) ? s[t - off] : 0;
        __syncthreads();
        s[t] += u;
        __syncthreads();
    }
    if (t < NB) boff[t] = s[t] - c;      // exclusive
    if (t == 0) { int tot = s[MAXB - 1]; boff[NB] = tot; offsets[N] = tot; }
    if (t < Npad - N) dinv[N + t] = 0.f; // pad rows
}

// one block per bucket: counting-sort by local dst -> csr (coalesced 8KB
// window), write offsets + dinv for the bucket's 128 nodes.
__global__ __launch_bounds__(256) void k_bsort(const int* __restrict__ boff,
                                               const int* __restrict__ bcnt,
                                               const unsigned* __restrict__ ppack,
                                               int* __restrict__ csr, int* __restrict__ offsets,
                                               float* __restrict__ dinv, int N) {
    __shared__ int h[BKT_NODES], base[BKT_NODES], s[BKT_NODES];
    int b = blockIdx.x;
    int ebase = boff[b], cnt = bcnt[b];
    const unsigned* pp = ppack + (size_t)b * CAP;
    int t = threadIdx.x;
    if (t < BKT_NODES) h[t] = 0;
    __syncthreads();
    for (int e = t; e < cnt; e += 256) atomicAdd(&h[pp[e] >> 25], 1);
    __syncthreads();
    int v = (t < BKT_NODES) ? h[t] : 0;
    if (t < BKT_NODES) s[t] = v;
    __syncthreads();
    for (int off = 1; off < BKT_NODES; off <<= 1) {
        int u = (t < BKT_NODES && t >= off) ? s[t - off] : 0;
        __syncthreads();
        if (t < BKT_NODES) s[t] += u;
        __syncthreads();
    }
    if (t < BKT_NODES) {
        int excl = s[t] - v;
        base[t] = excl;
        int node = b * BKT_NODES + t;
        if (node < N) {
            offsets[node] = ebase + excl;
            dinv[node] = rsqrtf((float)(v + 1));
        }
        h[t] = 0;   // reuse as cursor
    }
    __syncthreads();
    for (int e = t; e < cnt; e += 256) {
        unsigned pk = pp[e];
        int ld = pk >> 25;
        int pos = ebase + base[ld] + atomicAdd(&h[ld], 1);
        csr[pos] = (int)(pk & 0x1FFFFFFu);
    }
}

// ---------------- xs = dinv * x  (bf16 rows, pad rows zeroed) ----------------

__global__ __launch_bounds__(256) void k_prescale_x(
        const void* __restrict__ xraw, const float* __restrict__ dinv,
        const int* __restrict__ flags, __hip_bfloat162* __restrict__ xs2,
        int N, int Npad) {
    int gid = blockIdx.x * 256 + threadIdx.x;
    int v = gid >> 6, lane = gid & 63;
    if (v >= Npad) return;
    __hip_bfloat162 val;
    if (v < N) {
        float dv = dinv[v];
        float2 t = flags[0] ? ((const float2*)xraw)[(size_t)v * 64 + lane]
                            : bf2f(((const __hip_bfloat162*)xraw)[(size_t)v * 64 + lane]);
        val = f2bf(dv * t.x, dv * t.y);
    } else val = f2bf(0.f, 0.f);
    xs2[(size_t)v * 64 + lane] = val;
}

// ---------------- aggregation 1: a1[v] = dv*(xs[v] + sum xs[csr]) ----------------

__global__ __launch_bounds__(256) void k_agg1(
        const __hip_bfloat162* __restrict__ xs2, const int* __restrict__ offsets,
        const int* __restrict__ csr, const float* __restrict__ dinv,
        __hip_bfloat162* __restrict__ a2, int N, int Npad, int nwaves) {
    int gw   = blockIdx.x * 4 + (threadIdx.x >> 6);
    int lane = threadIdx.x & 63;
    for (int v = gw; v < Npad; v += nwaves) {
        if (v >= N) { a2[(size_t)v * 64 + lane] = f2bf(0.f, 0.f); continue; }
        float2 s0v = bf2f(xs2[(size_t)v * 64 + lane]);
        float ax = s0v.x, ay = s0v.y;
        int e = offsets[v], o1 = offsets[v + 1];
        for (; e + 3 < o1; e += 4) {
            int s0 = csr[e], s1 = csr[e + 1], s2 = csr[e + 2], s3 = csr[e + 3];
            float2 t0 = bf2f(xs2[(size_t)s0 * 64 + lane]);
            float2 t1 = bf2f(xs2[(size_t)s1 * 64 + lane]);
            float2 t2 = bf2f(xs2[(size_t)s2 * 64 + lane]);
            float2 t3 = bf2f(xs2[(size_t)s3 * 64 + lane]);
            ax += (t0.x + t1.x) + (t2.x + t3.x);
            ay += (t0.y + t1.y) + (t2.y + t3.y);
        }
        for (; e < o1; ++e) {
            int s = csr[e];
            float2 t = bf2f(xs2[(size_t)s * 64 + lane]);
            ax += t.x; ay += t.y;
        }
        float dv = dinv[v];
        a2[(size_t)v * 64 + lane] = f2bf(dv * ax, dv * ay);
    }
}

// ---------------- MFMA GEMM: C[M,NN] = A[M,K] @ W[K,NN] (+epilogue) ----------------
// Block = 4 waves, wave owns 32 rows (2 A-frag sets share each B-frag load).

template <int K, int NN, bool RELU_BIAS>
__global__ __launch_bounds__(256) void k_gemm(
        const __hip_bfloat16* __restrict__ A, const __hip_bfloat16* __restrict__ Bsw,
        const __hip_bfloat16* __restrict__ bias, const float* __restrict__ dinv,
        __hip_bfloat16* __restrict__ C) {
    constexpr int KC = K / 32;
    constexpr int NT = NN / 16;
    int wave = threadIdx.x >> 6, lane = threadIdx.x & 63;
    int quad = lane >> 4, l16 = lane & 15;
    int m0 = blockIdx.x * 128 + wave * 32;

    bf16x8v a[2][KC];
#pragma unroll
    for (int st = 0; st < 2; ++st)
#pragma unroll
        for (int kc = 0; kc < KC; ++kc)
            a[st][kc] = *reinterpret_cast<const bf16x8v*>(
                A + (size_t)(m0 + st * 16 + l16) * K + kc * 32 + quad * 8);

    const bf16x8v* B8 = reinterpret_cast<const bf16x8v*>(Bsw);
    int rb0 = m0 + quad * 4, rb1 = m0 + 16 + quad * 4;
    float sc0[4], sc1[4];
    if (!RELU_BIAS) {
#pragma unroll
        for (int r = 0; r < 4; ++r) { sc0[r] = dinv[rb0 + r]; sc1[r] = dinv[rb1 + r]; }
    }

    for (int nt = 0; nt < NT; ++nt) {
        f32x4 acc0 = {0.f, 0.f, 0.f, 0.f}, acc1 = {0.f, 0.f, 0.f, 0.f};
#pragma unroll
        for (int kc = 0; kc < KC; ++kc) {
            bf16x8v bfrag = B8[(nt * KC + kc) * 64 + lane];
            acc0 = __builtin_amdgcn_mfma_f32_16x16x32_bf16(a[0][kc], bfrag, acc0, 0, 0, 0);
            acc1 = __builtin_amdgcn_mfma_f32_16x16x32_bf16(a[1][kc], bfrag, acc1, 0, 0, 0);
        }
        int col = nt * 16 + l16;
        if (RELU_BIAS) {
            float bv = __bfloat162float(bias[col]);
#pragma unroll
            for (int r = 0; r < 4; ++r) {
                float v0 = acc0[r] + bv; v0 = v0 > 0.f ? v0 : 0.f;
                float v1 = acc1[r] + bv; v1 = v1 > 0.f ? v1 : 0.f;
                C[(size_t)(rb0 + r) * NN + col] = __float2bfloat16(v0);
                C[(size_t)(rb1 + r) * NN + col] = __float2bfloat16(v1);
            }
        } else {
#pragma unroll
            for (int r = 0; r < 4; ++r) {
                C[(size_t)(rb0 + r) * NN + col] = __float2bfloat16(acc0[r] * sc0[r]);
                C[(size_t)(rb1 + r) * NN + col] = __float2bfloat16(acc1[r] * sc1[r]);
            }
        }
    }
}

// ---------------- aggregation 2: out[v] = dv*(h2s[v] + sum h2s[csr]) + b2 ----------------

__global__ __launch_bounds__(256) void k_agg2(
        const __hip_bfloat162* __restrict__ h22, const int* __restrict__ offsets,
        const int* __restrict__ csr, const float* __restrict__ dinv,
        const __hip_bfloat16* __restrict__ b2c, const int* __restrict__ flags,
        void* __restrict__ outraw, int N, int nwaves) {
    int gw   = blockIdx.x * 4 + (threadIdx.x >> 6);
    int lane = threadIdx.x & 63;
    int f32  = flags[0];
    float2 bb = bf2f(((const __hip_bfloat162*)b2c)[lane]);
    for (int v = gw; v < N; v += nwaves) {
        float2 a = bf2f(h22[(size_t)v * 64 + lane]);
        float ax = a.x, ay = a.y;
        int e = offsets[v], o1 = offsets[v + 1];
        for (; e + 3 < o1; e += 4) {
            int s0 = csr[e], s1 = csr[e + 1], s2 = csr[e + 2], s3 = csr[e + 3];
            float2 t0 = bf2f(h22[(size_t)s0 * 64 + lane]);
            float2 t1 = bf2f(h22[(size_t)s1 * 64 + lane]);
            float2 t2 = bf2f(h22[(size_t)s2 * 64 + lane]);
            float2 t3 = bf2f(h22[(size_t)s3 * 64 + lane]);
            ax += (t0.x + t1.x) + (t2.x + t3.x);
            ay += (t0.y + t1.y) + (t2.y + t3.y);
        }
        for (; e < o1; ++e) {
            int s = csr[e];
            float2 t = bf2f(h22[(size_t)s * 64 + lane]);
            ax += t.x; ay += t.y;
        }
        float dv = dinv[v];
        float ox = dv * ax + bb.x, oy = dv * ay + bb.y;
        if (f32) ((float2*)outraw)[(size_t)v * 64 + lane] = make_float2(ox, oy);
        else     ((__hip_bfloat162*)outraw)[(size_t)v * 64 + lane] = f2bf(ox, oy);
    }
}

// ---------------- host launch ----------------

extern "C" void kernel_launch(void* const* d_in, const int* in_sizes, int n_in,
                              void* d_out, int out_size, void* d_ws, size_t ws_size,
                              hipStream_t stream) {
    const void* x  = d_in[0];
    const void* ei = d_in[1];
    const void* W1 = d_in[2];
    const void* b1 = d_in[3];
    const void* W2 = d_in[4];
    const void* b2 = d_in[5];

    const int N = in_sizes[0] / IN_DIM;       // 50000
    const int E = in_sizes[1] / 2;            // 800000
    const int Npad = ((N + 127) / 128) * 128; // 50048 (multiple of 128)
    const int NB = (N + BKT_NODES - 1) / BKT_NODES;   // 391

    char* w = (char*)d_ws;
    auto alloc = [&](size_t bytes) -> void* {
        void* p = (void*)w;
        w += (bytes + 255) / 256 * 256;
        return p;
    };
    int*   flags   = (int*)alloc(256);
    int*   bcnt    = (int*)alloc((size_t)MAXB * 4);
    int*   boff    = (int*)alloc((size_t)(MAXB + 1) * 4);
    int*   offsets = (int*)alloc((size_t)(N + 1) * 4);
    float* dinv    = (float*)alloc((size_t)Npad * 4);
    unsigned* ppack = (unsigned*)alloc((size_t)NB * CAP * 4);
    int*   csr     = (int*)alloc((size_t)E * 4);
    short* Bsw1 = (short*)alloc((size_t)IN_DIM * HID * 2);
    short* Bsw2 = (short*)alloc((size_t)HID * OUTD * 2);
    __hip_bfloat16* b1c = (__hip_bfloat16*)alloc((size_t)HID * 2);
    __hip_bfloat16* b2c = (__hip_bfloat16*)alloc((size_t)OUTD * 2);
    __hip_bfloat16* xs  = (__hip_bfloat16*)alloc((size_t)Npad * IN_DIM * 2);
    __hip_bfloat16* a1  = (__hip_bfloat16*)alloc((size_t)Npad * IN_DIM * 2);
    __hip_bfloat16* h1  = (__hip_bfloat16*)alloc((size_t)Npad * HID * 2);
    __hip_bfloat16* h2s = xs;   // xs dead after agg1; reuse for GEMM2 output

    k_detect<<<1, 64, 0, stream>>>(W2, ei, flags);
    hipMemsetAsync(bcnt, 0, (size_t)MAXB * 4, stream);

    k_prep_w<<<33, 256, 0, stream>>>(W1, b1, W2, b2, flags, Bsw1, Bsw2, b1c, b2c);

    k_edges<<<64, 256, 0, stream>>>(ei, E, N, NB, flags, bcnt, ppack);
    k_bscan<<<1, MAXB, 0, stream>>>(bcnt, NB, boff, offsets, dinv, N, Npad);
    k_bsort<<<NB, 256, 0, stream>>>(boff, bcnt, ppack, csr, offsets, dinv, N);

    k_prescale_x<<<(Npad * 64 + 255) / 256, 256, 0, stream>>>(x, dinv, flags,
                                                              (__hip_bfloat162*)xs, N, Npad);

    const int aggBlocks = 2048, nwaves = aggBlocks * 4;
    k_agg1<<<aggBlocks, 256, 0, stream>>>((const __hip_bfloat162*)xs, offsets, csr, dinv,
                                          (__hip_bfloat162*)a1, N, Npad, nwaves);

    k_gemm<IN_DIM, HID, true><<<Npad / 128, 256, 0, stream>>>(
        a1, (const __hip_bfloat16*)Bsw1, b1c, nullptr, h1);
    k_gemm<HID, OUTD, false><<<Npad / 128, 256, 0, stream>>>(
        h1, (const __hip_bfloat16*)Bsw2, nullptr, dinv, h2s);

    k_agg2<<<aggBlocks, 256, 0, stream>>>((const __hip_bfloat162*)h2s, offsets, csr, dinv,
                                          b2c, flags, d_out, N, nwaves);
}

// Round 6
// 233.640 us; speedup vs baseline: 4.5494x; 1.0824x over previous
//
#include <hip/hip_runtime.h>
#include <hip/hip_bf16.h>

// GCN 2-layer encoder, MI355X (gfx950).
// Known: float tensors bf16, edge_index int64 (detection kept, ~1us).
// Round 6: k_edges 512 blocks + wave-privatized LDS hist/cursors (was 2.4%
// occupancy + 184k LDS conflicts); k_detect parallel ballot; prescale fused
// into k_bsort. 8 dispatches.
// Pipeline:
//   k_prep_w: Bsw1/Bsw2 (MFMA B-frag order) + b1c/b2c
//   k_edges -> k_bscan -> k_bsort(+prescale xs=dinv*x): CSR/offsets/dinv/xs
//   a1[v] = dinv[v]*(xs[v] + sum xs[csr])     [gather]
//   h1 = relu(a1 @ W1 + b1)                    [MFMA]
//   h2s = (h1 @ W2) * dinv[row]                [MFMA]
//   out[v] = dinv[v]*(h2s[v] + sum h2s[csr]) + b2

typedef __bf16 bf16x8v __attribute__((ext_vector_type(8)));
typedef short  s16x8   __attribute__((ext_vector_type(8)));
typedef float  f32x4   __attribute__((ext_vector_type(4)));

#define IN_DIM 128
#define HID    256
#define OUTD   128
#define BKT_SHIFT 7
#define BKT_NODES 128
#define MAXB 512            // max buckets (N <= 65536)
#define CAP  8192           // per-bucket capacity (mean 2046, 40+ sigma margin)
#define EBLK 512            // k_edges grid

__device__ __forceinline__ float2 bf2f(__hip_bfloat162 v) {
    return make_float2(__bfloat162float(v.x), __bfloat162float(v.y));
}
__device__ __forceinline__ __hip_bfloat162 f2bf(float a, float b) {
    __hip_bfloat162 r; r.x = __float2bfloat16(a); r.y = __float2bfloat16(b); return r;
}

// ---------------- dtype detection (64-lane ballot) ----------------
__global__ void k_detect(const void* W2raw, const void* eiraw, int* flags) {
    int lane = threadIdx.x;
    const unsigned short* u = (const unsigned short*)W2raw;
    unsigned e = (u[lane] >> 7) & 0xFF;                 // bf16 exponent field
    unsigned long long m1 = __ballot(e >= 0x7F);        // any => fp32 buffer
    const unsigned* ip = (const unsigned*)eiraw;
    unsigned long long m2 = __ballot(ip[2 * lane + 1] != 0);  // any => int32
    if (lane == 0) {
        flags[0] = (m1 != 0) ? 1 : 0;
        flags[1] = (m2 == 0) ? 1 : 0;
    }
}

// ---------------- fused weight prep ----------------
// Bsw[(nt*KC+kc)*64 + lane][j] = W[kc*32 + (lane>>4)*8 + j][nt*16 + (lane&15)]

__device__ __forceinline__ short ldw(const void* raw, int idx, int f32) {
    if (f32) {
        __hip_bfloat16 h = __float2bfloat16(((const float*)raw)[idx]);
        return *(short*)&h;
    }
    return ((const short*)raw)[idx];
}

template <int K, int NN>
__device__ __forceinline__ void swz_one(const void* Wraw, int f32,
                                        short* __restrict__ Bsw, int tid) {
    constexpr int KC = K / 32;
    constexpr int NT = NN / 16;
    if (tid >= NT * KC * 64) return;
    int lane = tid & 63;
    int kc   = (tid >> 6) % KC;
    int nt   = tid / (64 * KC);
    int n  = nt * 16 + (lane & 15);
    int kb = kc * 32 + (lane >> 4) * 8;
    s16x8 v;
#pragma unroll
    for (int j = 0; j < 8; ++j) v[j] = ldw(Wraw, (kb + j) * NN + n, f32);
    ((s16x8*)Bsw)[tid] = v;
}

__global__ __launch_bounds__(256) void k_prep_w(
        const void* W1raw, const void* b1raw, const void* W2raw, const void* b2raw,
        const int* __restrict__ flags, short* __restrict__ Bsw1, short* __restrict__ Bsw2,
        __hip_bfloat16* __restrict__ b1c, __hip_bfloat16* __restrict__ b2c) {
    int f32 = flags[0];
    int blk = blockIdx.x, t = threadIdx.x;
    if (blk < 16) {
        swz_one<IN_DIM, HID>(W1raw, f32, Bsw1, blk * 256 + t);
    } else if (blk < 32) {
        swz_one<HID, OUTD>(W2raw, f32, Bsw2, (blk - 16) * 256 + t);
    } else {
        short s1 = ldw(b1raw, t, f32);
        b1c[t] = *(__hip_bfloat16*)&s1;
        if (t < OUTD) {
            short s2 = ldw(b2raw, t, f32);
            b2c[t] = *(__hip_bfloat16*)&s2;
        }
    }
}

// ---------------- one-pass edge bucketing (wave-privatized) ----------------
// Packs (ldst<<25)|src per edge into bucket regions ppack[b*CAP..]; bcnt[b]=count.

__global__ __launch_bounds__(256) void k_edges(
        const void* __restrict__ ei_, int E, int N, int NB,
        const int* __restrict__ flags, int* __restrict__ bcnt,
        unsigned* __restrict__ ppack) {
    __shared__ int lhist[4][MAXB];
    __shared__ int lbase[4][MAXB];
    int wv = threadIdx.x >> 6;
    int i64 = flags[1];
    const long long* p64 = (const long long*)ei_;
    const int*       p32 = (const int*)ei_;
    int per = (E + gridDim.x - 1) / gridDim.x;
    int e0 = blockIdx.x * per, e1 = min(e0 + per, E);
    for (int i = threadIdx.x; i < NB; i += 256) {
        lhist[0][i] = 0; lhist[1][i] = 0; lhist[2][i] = 0; lhist[3][i] = 0;
    }
    __syncthreads();
    for (int e = e0 + threadIdx.x; e < e1; e += 256) {
        int d = i64 ? (int)p64[E + e] : p32[E + e];
        if ((unsigned)d >= (unsigned)N) d = 0;
        atomicAdd(&lhist[wv][((unsigned)d) >> BKT_SHIFT], 1);
    }
    __syncthreads();
    for (int i = threadIdx.x; i < NB; i += 256) {
        int c0 = lhist[0][i], c1 = lhist[1][i], c2 = lhist[2][i], c3 = lhist[3][i];
        int tot = c0 + c1 + c2 + c3;
        int g = tot ? atomicAdd(&bcnt[i], tot) : 0;
        lbase[0][i] = g;
        lbase[1][i] = g + c0;
        lbase[2][i] = g + c0 + c1;
        lbase[3][i] = g + c0 + c1 + c2;
        lhist[0][i] = 0; lhist[1][i] = 0; lhist[2][i] = 0; lhist[3][i] = 0;
    }
    __syncthreads();
    for (int e = e0 + threadIdx.x; e < e1; e += 256) {
        int d = i64 ? (int)p64[E + e] : p32[E + e];
        int s = i64 ? (int)p64[e]     : p32[e];
        if ((unsigned)d >= (unsigned)N) d = 0;
        if ((unsigned)s >= (unsigned)N) s = 0;
        int b = ((unsigned)d) >> BKT_SHIFT;
        int pos = lbase[wv][b] + atomicAdd(&lhist[wv][b], 1);
        if (pos < CAP)
            ppack[(size_t)b * CAP + pos] = ((unsigned)(d & (BKT_NODES - 1)) << 25) | (unsigned)s;
    }
}

__global__ __launch_bounds__(512) void k_bscan(int* __restrict__ bcnt, int NB,
                                               int* __restrict__ boff,
                                               int* __restrict__ offsets, float* __restrict__ dinv,
                                               int N, int Npad) {
    __shared__ int s[MAXB];
    int t = threadIdx.x;
    int c = (t < NB) ? min(bcnt[t], CAP) : 0;
    if (t < NB) bcnt[t] = c;             // clamp (overflow never expected)
    s[t] = c; __syncthreads();
    for (int off = 1; off < MAXB; off <<= 1) {
        int u = (t >= off) ? s[t - off] : 0;
        __syncthreads();
        s[t] += u;
        __syncthreads();
    }
    if (t < NB) boff[t] = s[t] - c;      // exclusive
    if (t == 0) { int tot = s[MAXB - 1]; boff[NB] = tot; offsets[N] = tot; }
    if (t < Npad - N) dinv[N + t] = 0.f; // pad rows
}

// one block per bucket: counting-sort by local dst -> csr (coalesced 8KB
// window), offsets + dinv for its 128 nodes, then xs = dinv*x for its rows.
__global__ __launch_bounds__(256) void k_bsort(const int* __restrict__ boff,
                                               const int* __restrict__ bcnt,
                                               const unsigned* __restrict__ ppack,
                                               int* __restrict__ csr, int* __restrict__ offsets,
                                               float* __restrict__ dinv, int N,
                                               const void* __restrict__ xraw,
                                               const int* __restrict__ flags,
                                               __hip_bfloat16* __restrict__ xs) {
    __shared__ int h[BKT_NODES], base[BKT_NODES], s[BKT_NODES];
    __shared__ float sdv[BKT_NODES];
    int b = blockIdx.x;
    int ebase = boff[b], cnt = bcnt[b];
    const unsigned* pp = ppack + (size_t)b * CAP;
    int t = threadIdx.x;
    if (t < BKT_NODES) h[t] = 0;
    __syncthreads();
    for (int e = t; e < cnt; e += 256) atomicAdd(&h[pp[e] >> 25], 1);
    __syncthreads();
    int v = (t < BKT_NODES) ? h[t] : 0;
    if (t < BKT_NODES) s[t] = v;
    __syncthreads();
    for (int off = 1; off < BKT_NODES; off <<= 1) {
        int u = (t < BKT_NODES && t >= off) ? s[t - off] : 0;
        __syncthreads();
        if (t < BKT_NODES) s[t] += u;
        __syncthreads();
    }
    if (t < BKT_NODES) {
        int excl = s[t] - v;
        base[t] = excl;
        int node = b * BKT_NODES + t;
        float dv = 0.f;
        if (node < N) {
            dv = rsqrtf((float)(v + 1));
            offsets[node] = ebase + excl;
            dinv[node] = dv;
        }
        sdv[t] = dv;
        h[t] = 0;   // reuse as cursor
    }
    __syncthreads();
    for (int e = t; e < cnt; e += 256) {
        unsigned pk = pp[e];
        int ld = pk >> 25;
        int pos = ebase + base[ld] + atomicAdd(&h[ld], 1);
        csr[pos] = (int)(pk & 0x1FFFFFFu);
    }
    // fused prescale: xs rows [b*128, b*128+128) = dinv * x
    int f32 = flags[0];
    if (!f32) {
        const s16x8* xg = (const s16x8*)xraw;           // 16 units of 8 bf16 per row
        s16x8* xo = (s16x8*)xs;
        for (int u = t; u < BKT_NODES * 16; u += 256) {
            int row = u >> 4;
            int node = b * BKT_NODES + row;
            float dv = sdv[row];
            s16x8 val = {0, 0, 0, 0, 0, 0, 0, 0};
            if (node < N) {
                s16x8 xin = xg[(size_t)node * 16 + (u & 15)];
                __hip_bfloat162* xp = (__hip_bfloat162*)&xin;
                __hip_bfloat162* vp = (__hip_bfloat162*)&val;
#pragma unroll
                for (int j = 0; j < 4; ++j) {
                    float2 f = bf2f(xp[j]);
                    vp[j] = f2bf(dv * f.x, dv * f.y);
                }
            }
            xo[(size_t)node * 16 + (u & 15)] = val;
        }
    } else {
        const float4* xg = (const float4*)xraw;         // 32 units of 4 f32 per row
        __hip_bfloat162* xo = (__hip_bfloat162*)xs;
        for (int u = t; u < BKT_NODES * 32; u += 256) {
            int row = u >> 5;
            int node = b * BKT_NODES + row;
            float dv = sdv[row];
            __hip_bfloat162 v0 = f2bf(0.f, 0.f), v1 = v0;
            if (node < N) {
                float4 xin = xg[(size_t)node * 32 + (u & 31)];
                v0 = f2bf(dv * xin.x, dv * xin.y);
                v1 = f2bf(dv * xin.z, dv * xin.w);
            }
            xo[(size_t)node * 64 + (u & 31) * 2]     = v0;
            xo[(size_t)node * 64 + (u & 31) * 2 + 1] = v1;
        }
    }
}

// ---------------- aggregation 1: a1[v] = dv*(xs[v] + sum xs[csr]) ----------------

__global__ __launch_bounds__(256) void k_agg1(
        const __hip_bfloat162* __restrict__ xs2, const int* __restrict__ offsets,
        const int* __restrict__ csr, const float* __restrict__ dinv,
        __hip_bfloat162* __restrict__ a2, int N, int Npad, int nwaves) {
    int gw   = blockIdx.x * 4 + (threadIdx.x >> 6);
    int lane = threadIdx.x & 63;
    for (int v = gw; v < Npad; v += nwaves) {
        if (v >= N) { a2[(size_t)v * 64 + lane] = f2bf(0.f, 0.f); continue; }
        float2 s0v = bf2f(xs2[(size_t)v * 64 + lane]);
        float ax = s0v.x, ay = s0v.y;
        int e = offsets[v], o1 = offsets[v + 1];
        for (; e + 3 < o1; e += 4) {
            int s0 = csr[e], s1 = csr[e + 1], s2 = csr[e + 2], s3 = csr[e + 3];
            float2 t0 = bf2f(xs2[(size_t)s0 * 64 + lane]);
            float2 t1 = bf2f(xs2[(size_t)s1 * 64 + lane]);
            float2 t2 = bf2f(xs2[(size_t)s2 * 64 + lane]);
            float2 t3 = bf2f(xs2[(size_t)s3 * 64 + lane]);
            ax += (t0.x + t1.x) + (t2.x + t3.x);
            ay += (t0.y + t1.y) + (t2.y + t3.y);
        }
        for (; e < o1; ++e) {
            int s = csr[e];
            float2 t = bf2f(xs2[(size_t)s * 64 + lane]);
            ax += t.x; ay += t.y;
        }
        float dv = dinv[v];
        a2[(size_t)v * 64 + lane] = f2bf(dv * ax, dv * ay);
    }
}

// ---------------- MFMA GEMM: C[M,NN] = A[M,K] @ W[K,NN] (+epilogue) ----------------
// Block = 4 waves, wave owns 32 rows (2 A-frag sets share each B-frag load).

template <int K, int NN, bool RELU_BIAS>
__global__ __launch_bounds__(256) void k_gemm(
        const __hip_bfloat16* __restrict__ A, const __hip_bfloat16* __restrict__ Bsw,
        const __hip_bfloat16* __restrict__ bias, const float* __restrict__ dinv,
        __hip_bfloat16* __restrict__ C) {
    constexpr int KC = K / 32;
    constexpr int NT = NN / 16;
    int wave = threadIdx.x >> 6, lane = threadIdx.x & 63;
    int quad = lane >> 4, l16 = lane & 15;
    int m0 = blockIdx.x * 128 + wave * 32;

    bf16x8v a[2][KC];
#pragma unroll
    for (int st = 0; st < 2; ++st)
#pragma unroll
        for (int kc = 0; kc < KC; ++kc)
            a[st][kc] = *reinterpret_cast<const bf16x8v*>(
                A + (size_t)(m0 + st * 16 + l16) * K + kc * 32 + quad * 8);

    const bf16x8v* B8 = reinterpret_cast<const bf16x8v*>(Bsw);
    int rb0 = m0 + quad * 4, rb1 = m0 + 16 + quad * 4;
    float sc0[4], sc1[4];
    if (!RELU_BIAS) {
#pragma unroll
        for (int r = 0; r < 4; ++r) { sc0[r] = dinv[rb0 + r]; sc1[r] = dinv[rb1 + r]; }
    }

    for (int nt = 0; nt < NT; ++nt) {
        f32x4 acc0 = {0.f, 0.f, 0.f, 0.f}, acc1 = {0.f, 0.f, 0.f, 0.f};
#pragma unroll
        for (int kc = 0; kc < KC; ++kc) {
            bf16x8v bfrag = B8[(nt * KC + kc) * 64 + lane];
            acc0 = __builtin_amdgcn_mfma_f32_16x16x32_bf16(a[0][kc], bfrag, acc0, 0, 0, 0);
            acc1 = __builtin_amdgcn_mfma_f32_16x16x32_bf16(a[1][kc], bfrag, acc1, 0, 0, 0);
        }
        int col = nt * 16 + l16;
        if (RELU_BIAS) {
            float bv = __bfloat162float(bias[col]);
#pragma unroll
            for (int r = 0; r < 4; ++r) {
                float v0 = acc0[r] + bv; v0 = v0 > 0.f ? v0 : 0.f;
                float v1 = acc1[r] + bv; v1 = v1 > 0.f ? v1 : 0.f;
                C[(size_t)(rb0 + r) * NN + col] = __float2bfloat16(v0);
                C[(size_t)(rb1 + r) * NN + col] = __float2bfloat16(v1);
            }
        } else {
#pragma unroll
            for (int r = 0; r < 4; ++r) {
                C[(size_t)(rb0 + r) * NN + col] = __float2bfloat16(acc0[r] * sc0[r]);
                C[(size_t)(rb1 + r) * NN + col] = __float2bfloat16(acc1[r] * sc1[r]);
            }
        }
    }
}

// ---------------- aggregation 2: out[v] = dv*(h2s[v] + sum h2s[csr]) + b2 ----------------

__global__ __launch_bounds__(256) void k_agg2(
        const __hip_bfloat162* __restrict__ h22, const int* __restrict__ offsets,
        const int* __restrict__ csr, const float* __restrict__ dinv,
        const __hip_bfloat16* __restrict__ b2c, const int* __restrict__ flags,
        void* __restrict__ outraw, int N, int nwaves) {
    int gw   = blockIdx.x * 4 + (threadIdx.x >> 6);
    int lane = threadIdx.x & 63;
    int f32  = flags[0];
    float2 bb = bf2f(((const __hip_bfloat162*)b2c)[lane]);
    for (int v = gw; v < N; v += nwaves) {
        float2 a = bf2f(h22[(size_t)v * 64 + lane]);
        float ax = a.x, ay = a.y;
        int e = offsets[v], o1 = offsets[v + 1];
        for (; e + 3 < o1; e += 4) {
            int s0 = csr[e], s1 = csr[e + 1], s2 = csr[e + 2], s3 = csr[e + 3];
            float2 t0 = bf2f(h22[(size_t)s0 * 64 + lane]);
            float2 t1 = bf2f(h22[(size_t)s1 * 64 + lane]);
            float2 t2 = bf2f(h22[(size_t)s2 * 64 + lane]);
            float2 t3 = bf2f(h22[(size_t)s3 * 64 + lane]);
            ax += (t0.x + t1.x) + (t2.x + t3.x);
            ay += (t0.y + t1.y) + (t2.y + t3.y);
        }
        for (; e < o1; ++e) {
            int s = csr[e];
            float2 t = bf2f(h22[(size_t)s * 64 + lane]);
            ax += t.x; ay += t.y;
        }
        float dv = dinv[v];
        float ox = dv * ax + bb.x, oy = dv * ay + bb.y;
        if (f32) ((float2*)outraw)[(size_t)v * 64 + lane] = make_float2(ox, oy);
        else     ((__hip_bfloat162*)outraw)[(size_t)v * 64 + lane] = f2bf(ox, oy);
    }
}

// ---------------- host launch ----------------

extern "C" void kernel_launch(void* const* d_in, const int* in_sizes, int n_in,
                              void* d_out, int out_size, void* d_ws, size_t ws_size,
                              hipStream_t stream) {
    const void* x  = d_in[0];
    const void* ei = d_in[1];
    const void* W1 = d_in[2];
    const void* b1 = d_in[3];
    const void* W2 = d_in[4];
    const void* b2 = d_in[5];

    const int N = in_sizes[0] / IN_DIM;       // 50000
    const int E = in_sizes[1] / 2;            // 800000
    const int Npad = ((N + 127) / 128) * 128; // 50048 (multiple of 128)
    const int NB = (N + BKT_NODES - 1) / BKT_NODES;   // 391 (NB*128 == Npad)

    char* w = (char*)d_ws;
    auto alloc = [&](size_t bytes) -> void* {
        void* p = (void*)w;
        w += (bytes + 255) / 256 * 256;
        return p;
    };
    int*   flags   = (int*)alloc(256);
    int*   bcnt    = (int*)alloc((size_t)MAXB * 4);
    int*   boff    = (int*)alloc((size_t)(MAXB + 1) * 4);
    int*   offsets = (int*)alloc((size_t)(N + 1) * 4);
    float* dinv    = (float*)alloc((size_t)Npad * 4);
    unsigned* ppack = (unsigned*)alloc((size_t)NB * CAP * 4);
    int*   csr     = (int*)alloc((size_t)E * 4);
    short* Bsw1 = (short*)alloc((size_t)IN_DIM * HID * 2);
    short* Bsw2 = (short*)alloc((size_t)HID * OUTD * 2);
    __hip_bfloat16* b1c = (__hip_bfloat16*)alloc((size_t)HID * 2);
    __hip_bfloat16* b2c = (__hip_bfloat16*)alloc((size_t)OUTD * 2);
    __hip_bfloat16* xs  = (__hip_bfloat16*)alloc((size_t)Npad * IN_DIM * 2);
    __hip_bfloat16* a1  = (__hip_bfloat16*)alloc((size_t)Npad * IN_DIM * 2);
    __hip_bfloat16* h1  = (__hip_bfloat16*)alloc((size_t)Npad * HID * 2);
    __hip_bfloat16* h2s = xs;   // xs dead after agg1; reuse for GEMM2 output

    k_detect<<<1, 64, 0, stream>>>(W2, ei, flags);
    hipMemsetAsync(bcnt, 0, (size_t)MAXB * 4, stream);

    k_prep_w<<<33, 256, 0, stream>>>(W1, b1, W2, b2, flags, Bsw1, Bsw2, b1c, b2c);

    k_edges<<<EBLK, 256, 0, stream>>>(ei, E, N, NB, flags, bcnt, ppack);
    k_bscan<<<1, MAXB, 0, stream>>>(bcnt, NB, boff, offsets, dinv, N, Npad);
    k_bsort<<<NB, 256, 0, stream>>>(boff, bcnt, ppack, csr, offsets, dinv, N,
                                    x, flags, xs);

    const int aggBlocks = 2048, nwaves = aggBlocks * 4;
    k_agg1<<<aggBlocks, 256, 0, stream>>>((const __hip_bfloat162*)xs, offsets, csr, dinv,
                                          (__hip_bfloat162*)a1, N, Npad, nwaves);

    k_gemm<IN_DIM, HID, true><<<Npad / 128, 256, 0, stream>>>(
        a1, (const __hip_bfloat16*)Bsw1, b1c, nullptr, h1);
    k_gemm<HID, OUTD, false><<<Npad / 128, 256, 0, stream>>>(
        h1, (const __hip_bfloat16*)Bsw2, nullptr, dinv, h2s);

    k_agg2<<<aggBlocks, 256, 0, stream>>>((const __hip_bfloat162*)h2s, offsets, csr, dinv,
                                          b2c, flags, d_out, N, nwaves);
}

// Round 7
// 224.239 us; speedup vs baseline: 4.7401x; 1.0419x over previous
//
#include <hip/hip_runtime.h>
#include <hip/hip_bf16.h>

// GCN 2-layer encoder, MI355X (gfx950).
// Known: float tensors bf16, edge_index int64 (detection kept, ~1us).
// Round 7: gather kernels restructured — 16B/lane loads, 16 lanes/row,
// 4 edge-groups/wave (4x MLP, 4x fewer load insts), cross-group shfl_xor
// reduce. Rest unchanged from round 6 (234us).
// Pipeline:
//   k_prep_w: Bsw1/Bsw2 (MFMA B-frag order) + b1c/b2c
//   k_edges -> k_bscan -> k_bsort(+prescale xs=dinv*x): CSR/offsets/dinv/xs
//   a1[v] = dinv[v]*(xs[v] + sum xs[csr])     [gather, grouped]
//   h1 = relu(a1 @ W1 + b1)                    [MFMA]
//   h2s = (h1 @ W2) * dinv[row]                [MFMA]
//   out[v] = dinv[v]*(h2s[v] + sum h2s[csr]) + b2   [gather, grouped]

typedef __bf16 bf16x8v __attribute__((ext_vector_type(8)));
typedef short  s16x8   __attribute__((ext_vector_type(8)));
typedef float  f32x4   __attribute__((ext_vector_type(4)));

#define IN_DIM 128
#define HID    256
#define OUTD   128
#define BKT_SHIFT 7
#define BKT_NODES 128
#define MAXB 512            // max buckets (N <= 65536)
#define CAP  8192           // per-bucket capacity (mean 2046, 40+ sigma margin)
#define EBLK 512            // k_edges grid

__device__ __forceinline__ float2 bf2f(__hip_bfloat162 v) {
    return make_float2(__bfloat162float(v.x), __bfloat162float(v.y));
}
__device__ __forceinline__ __hip_bfloat162 f2bf(float a, float b) {
    __hip_bfloat162 r; r.x = __float2bfloat16(a); r.y = __float2bfloat16(b); return r;
}
__device__ __forceinline__ void acc_row(float* acc, s16x8 r) {
    __hip_bfloat162* p = (__hip_bfloat162*)&r;
#pragma unroll
    for (int j = 0; j < 4; ++j) {
        float2 f = bf2f(p[j]);
        acc[2 * j]     += f.x;
        acc[2 * j + 1] += f.y;
    }
}

// ---------------- dtype detection (64-lane ballot) ----------------
__global__ void k_detect(const void* W2raw, const void* eiraw, int* flags) {
    int lane = threadIdx.x;
    const unsigned short* u = (const unsigned short*)W2raw;
    unsigned e = (u[lane] >> 7) & 0xFF;                 // bf16 exponent field
    unsigned long long m1 = __ballot(e >= 0x7F);        // any => fp32 buffer
    const unsigned* ip = (const unsigned*)eiraw;
    unsigned long long m2 = __ballot(ip[2 * lane + 1] != 0);  // any => int32
    if (lane == 0) {
        flags[0] = (m1 != 0) ? 1 : 0;
        flags[1] = (m2 == 0) ? 1 : 0;
    }
}

// ---------------- fused weight prep ----------------
// Bsw[(nt*KC+kc)*64 + lane][j] = W[kc*32 + (lane>>4)*8 + j][nt*16 + (lane&15)]

__device__ __forceinline__ short ldw(const void* raw, int idx, int f32) {
    if (f32) {
        __hip_bfloat16 h = __float2bfloat16(((const float*)raw)[idx]);
        return *(short*)&h;
    }
    return ((const short*)raw)[idx];
}

template <int K, int NN>
__device__ __forceinline__ void swz_one(const void* Wraw, int f32,
                                        short* __restrict__ Bsw, int tid) {
    constexpr int KC = K / 32;
    constexpr int NT = NN / 16;
    if (tid >= NT * KC * 64) return;
    int lane = tid & 63;
    int kc   = (tid >> 6) % KC;
    int nt   = tid / (64 * KC);
    int n  = nt * 16 + (lane & 15);
    int kb = kc * 32 + (lane >> 4) * 8;
    s16x8 v;
#pragma unroll
    for (int j = 0; j < 8; ++j) v[j] = ldw(Wraw, (kb + j) * NN + n, f32);
    ((s16x8*)Bsw)[tid] = v;
}

__global__ __launch_bounds__(256) void k_prep_w(
        const void* W1raw, const void* b1raw, const void* W2raw, const void* b2raw,
        const int* __restrict__ flags, short* __restrict__ Bsw1, short* __restrict__ Bsw2,
        __hip_bfloat16* __restrict__ b1c, __hip_bfloat16* __restrict__ b2c) {
    int f32 = flags[0];
    int blk = blockIdx.x, t = threadIdx.x;
    if (blk < 16) {
        swz_one<IN_DIM, HID>(W1raw, f32, Bsw1, blk * 256 + t);
    } else if (blk < 32) {
        swz_one<HID, OUTD>(W2raw, f32, Bsw2, (blk - 16) * 256 + t);
    } else {
        short s1 = ldw(b1raw, t, f32);
        b1c[t] = *(__hip_bfloat16*)&s1;
        if (t < OUTD) {
            short s2 = ldw(b2raw, t, f32);
            b2c[t] = *(__hip_bfloat16*)&s2;
        }
    }
}

// ---------------- one-pass edge bucketing (wave-privatized) ----------------

__global__ __launch_bounds__(256) void k_edges(
        const void* __restrict__ ei_, int E, int N, int NB,
        const int* __restrict__ flags, int* __restrict__ bcnt,
        unsigned* __restrict__ ppack) {
    __shared__ int lhist[4][MAXB];
    __shared__ int lbase[4][MAXB];
    int wv = threadIdx.x >> 6;
    int i64 = flags[1];
    const long long* p64 = (const long long*)ei_;
    const int*       p32 = (const int*)ei_;
    int per = (E + gridDim.x - 1) / gridDim.x;
    int e0 = blockIdx.x * per, e1 = min(e0 + per, E);
    for (int i = threadIdx.x; i < NB; i += 256) {
        lhist[0][i] = 0; lhist[1][i] = 0; lhist[2][i] = 0; lhist[3][i] = 0;
    }
    __syncthreads();
    for (int e = e0 + threadIdx.x; e < e1; e += 256) {
        int d = i64 ? (int)p64[E + e] : p32[E + e];
        if ((unsigned)d >= (unsigned)N) d = 0;
        atomicAdd(&lhist[wv][((unsigned)d) >> BKT_SHIFT], 1);
    }
    __syncthreads();
    for (int i = threadIdx.x; i < NB; i += 256) {
        int c0 = lhist[0][i], c1 = lhist[1][i], c2 = lhist[2][i], c3 = lhist[3][i];
        int tot = c0 + c1 + c2 + c3;
        int g = tot ? atomicAdd(&bcnt[i], tot) : 0;
        lbase[0][i] = g;
        lbase[1][i] = g + c0;
        lbase[2][i] = g + c0 + c1;
        lbase[3][i] = g + c0 + c1 + c2;
        lhist[0][i] = 0; lhist[1][i] = 0; lhist[2][i] = 0; lhist[3][i] = 0;
    }
    __syncthreads();
    for (int e = e0 + threadIdx.x; e < e1; e += 256) {
        int d = i64 ? (int)p64[E + e] : p32[E + e];
        int s = i64 ? (int)p64[e]     : p32[e];
        if ((unsigned)d >= (unsigned)N) d = 0;
        if ((unsigned)s >= (unsigned)N) s = 0;
        int b = ((unsigned)d) >> BKT_SHIFT;
        int pos = lbase[wv][b] + atomicAdd(&lhist[wv][b], 1);
        if (pos < CAP)
            ppack[(size_t)b * CAP + pos] = ((unsigned)(d & (BKT_NODES - 1)) << 25) | (unsigned)s;
    }
}

__global__ __launch_bounds__(512) void k_bscan(int* __restrict__ bcnt, int NB,
                                               int* __restrict__ boff,
                                               int* __restrict__ offsets, float* __restrict__ dinv,
                                               int N, int Npad) {
    __shared__ int s[MAXB];
    int t = threadIdx.x;
    int c = (t < NB) ? min(bcnt[t], CAP) : 0;
    if (t < NB) bcnt[t] = c;             // clamp (overflow never expected)
    s[t] = c; __syncthreads();
    for (int off = 1; off < MAXB; off <<= 1) {
        int u = (t >= off) ? s[t - off] : 0;
        __syncthreads();
        s[t] += u;
        __syncthreads();
    }
    if (t < NB) boff[t] = s[t] - c;      // exclusive
    if (t == 0) { int tot = s[MAXB - 1]; boff[NB] = tot; offsets[N] = tot; }
    if (t < Npad - N) dinv[N + t] = 0.f; // pad rows
}

// one block per bucket: counting-sort by local dst -> csr (coalesced 8KB
// window), offsets + dinv for its 128 nodes, then xs = dinv*x for its rows.
__global__ __launch_bounds__(256) void k_bsort(const int* __restrict__ boff,
                                               const int* __restrict__ bcnt,
                                               const unsigned* __restrict__ ppack,
                                               int* __restrict__ csr, int* __restrict__ offsets,
                                               float* __restrict__ dinv, int N,
                                               const void* __restrict__ xraw,
                                               const int* __restrict__ flags,
                                               __hip_bfloat16* __restrict__ xs) {
    __shared__ int h[BKT_NODES], base[BKT_NODES], s[BKT_NODES];
    __shared__ float sdv[BKT_NODES];
    int b = blockIdx.x;
    int ebase = boff[b], cnt = bcnt[b];
    const unsigned* pp = ppack + (size_t)b * CAP;
    int t = threadIdx.x;
    if (t < BKT_NODES) h[t] = 0;
    __syncthreads();
    for (int e = t; e < cnt; e += 256) atomicAdd(&h[pp[e] >> 25], 1);
    __syncthreads();
    int v = (t < BKT_NODES) ? h[t] : 0;
    if (t < BKT_NODES) s[t] = v;
    __syncthreads();
    for (int off = 1; off < BKT_NODES; off <<= 1) {
        int u = (t < BKT_NODES && t >= off) ? s[t - off] : 0;
        __syncthreads();
        if (t < BKT_NODES) s[t] += u;
        __syncthreads();
    }
    if (t < BKT_NODES) {
        int excl = s[t] - v;
        base[t] = excl;
        int node = b * BKT_NODES + t;
        float dv = 0.f;
        if (node < N) {
            dv = rsqrtf((float)(v + 1));
            offsets[node] = ebase + excl;
            dinv[node] = dv;
        }
        sdv[t] = dv;
        h[t] = 0;   // reuse as cursor
    }
    __syncthreads();
    for (int e = t; e < cnt; e += 256) {
        unsigned pk = pp[e];
        int ld = pk >> 25;
        int pos = ebase + base[ld] + atomicAdd(&h[ld], 1);
        csr[pos] = (int)(pk & 0x1FFFFFFu);
    }
    // fused prescale: xs rows [b*128, b*128+128) = dinv * x
    int f32 = flags[0];
    if (!f32) {
        const s16x8* xg = (const s16x8*)xraw;           // 16 units of 8 bf16 per row
        s16x8* xo = (s16x8*)xs;
        for (int u = t; u < BKT_NODES * 16; u += 256) {
            int row = u >> 4;
            int node = b * BKT_NODES + row;
            float dv = sdv[row];
            s16x8 val = {0, 0, 0, 0, 0, 0, 0, 0};
            if (node < N) {
                s16x8 xin = xg[(size_t)node * 16 + (u & 15)];
                __hip_bfloat162* xp = (__hip_bfloat162*)&xin;
                __hip_bfloat162* vp = (__hip_bfloat162*)&val;
#pragma unroll
                for (int j = 0; j < 4; ++j) {
                    float2 f = bf2f(xp[j]);
                    vp[j] = f2bf(dv * f.x, dv * f.y);
                }
            }
            xo[(size_t)node * 16 + (u & 15)] = val;
        }
    } else {
        const float4* xg = (const float4*)xraw;         // 32 units of 4 f32 per row
        __hip_bfloat162* xo = (__hip_bfloat162*)xs;
        for (int u = t; u < BKT_NODES * 32; u += 256) {
            int row = u >> 5;
            int node = b * BKT_NODES + row;
            float dv = sdv[row];
            __hip_bfloat162 v0 = f2bf(0.f, 0.f), v1 = v0;
            if (node < N) {
                float4 xin = xg[(size_t)node * 32 + (u & 31)];
                v0 = f2bf(dv * xin.x, dv * xin.y);
                v1 = f2bf(dv * xin.z, dv * xin.w);
            }
            xo[(size_t)node * 64 + (u & 31) * 2]     = v0;
            xo[(size_t)node * 64 + (u & 31) * 2 + 1] = v1;
        }
    }
}

// ---------------- aggregation 1 (grouped gather) ----------------
// 16 lanes per row (16B/lane), 4 edge-groups per wave, shfl_xor combine.

__global__ __launch_bounds__(256) void k_agg1(
        const s16x8* __restrict__ xs8, const int* __restrict__ offsets,
        const int* __restrict__ csr, const float* __restrict__ dinv,
        s16x8* __restrict__ a8, int N, int Npad, int nwaves) {
    int gw   = blockIdx.x * 4 + (threadIdx.x >> 6);
    int lane = threadIdx.x & 63;
    int g = lane >> 4, li = lane & 15;
    for (int v = gw; v < Npad; v += nwaves) {
        if (v >= N) {
            if (g == 0) { s16x8 z = {0,0,0,0,0,0,0,0}; a8[(size_t)v * 16 + li] = z; }
            continue;
        }
        float acc[8];
#pragma unroll
        for (int j = 0; j < 8; ++j) acc[j] = 0.f;
        int o0 = offsets[v], o1 = offsets[v + 1];
        if (g == 0) acc_row(acc, xs8[(size_t)v * 16 + li]);   // self (pre-scaled)
        int e = o0 + g;
        for (; e + 4 < o1; e += 8) {
            int s0 = csr[e], s1 = csr[e + 4];
            s16x8 r0 = xs8[(size_t)s0 * 16 + li];
            s16x8 r1 = xs8[(size_t)s1 * 16 + li];
            acc_row(acc, r0);
            acc_row(acc, r1);
        }
        if (e < o1) acc_row(acc, xs8[(size_t)csr[e] * 16 + li]);
#pragma unroll
        for (int j = 0; j < 8; ++j) {
            acc[j] += __shfl_xor(acc[j], 16, 64);
            acc[j] += __shfl_xor(acc[j], 32, 64);
        }
        if (g == 0) {
            float dv = dinv[v];
            s16x8 outv;
            __hip_bfloat162* op = (__hip_bfloat162*)&outv;
#pragma unroll
            for (int j = 0; j < 4; ++j) op[j] = f2bf(dv * acc[2 * j], dv * acc[2 * j + 1]);
            a8[(size_t)v * 16 + li] = outv;
        }
    }
}

// ---------------- MFMA GEMM: C[M,NN] = A[M,K] @ W[K,NN] (+epilogue) ----------------
// Block = 4 waves, wave owns 32 rows (2 A-frag sets share each B-frag load).

template <int K, int NN, bool RELU_BIAS>
__global__ __launch_bounds__(256) void k_gemm(
        const __hip_bfloat16* __restrict__ A, const __hip_bfloat16* __restrict__ Bsw,
        const __hip_bfloat16* __restrict__ bias, const float* __restrict__ dinv,
        __hip_bfloat16* __restrict__ C) {
    constexpr int KC = K / 32;
    constexpr int NT = NN / 16;
    int wave = threadIdx.x >> 6, lane = threadIdx.x & 63;
    int quad = lane >> 4, l16 = lane & 15;
    int m0 = blockIdx.x * 128 + wave * 32;

    bf16x8v a[2][KC];
#pragma unroll
    for (int st = 0; st < 2; ++st)
#pragma unroll
        for (int kc = 0; kc < KC; ++kc)
            a[st][kc] = *reinterpret_cast<const bf16x8v*>(
                A + (size_t)(m0 + st * 16 + l16) * K + kc * 32 + quad * 8);

    const bf16x8v* B8 = reinterpret_cast<const bf16x8v*>(Bsw);
    int rb0 = m0 + quad * 4, rb1 = m0 + 16 + quad * 4;
    float sc0[4], sc1[4];
    if (!RELU_BIAS) {
#pragma unroll
        for (int r = 0; r < 4; ++r) { sc0[r] = dinv[rb0 + r]; sc1[r] = dinv[rb1 + r]; }
    }

    for (int nt = 0; nt < NT; ++nt) {
        f32x4 acc0 = {0.f, 0.f, 0.f, 0.f}, acc1 = {0.f, 0.f, 0.f, 0.f};
#pragma unroll
        for (int kc = 0; kc < KC; ++kc) {
            bf16x8v bfrag = B8[(nt * KC + kc) * 64 + lane];
            acc0 = __builtin_amdgcn_mfma_f32_16x16x32_bf16(a[0][kc], bfrag, acc0, 0, 0, 0);
            acc1 = __builtin_amdgcn_mfma_f32_16x16x32_bf16(a[1][kc], bfrag, acc1, 0, 0, 0);
        }
        int col = nt * 16 + l16;
        if (RELU_BIAS) {
            float bv = __bfloat162float(bias[col]);
#pragma unroll
            for (int r = 0; r < 4; ++r) {
                float v0 = acc0[r] + bv; v0 = v0 > 0.f ? v0 : 0.f;
                float v1 = acc1[r] + bv; v1 = v1 > 0.f ? v1 : 0.f;
                C[(size_t)(rb0 + r) * NN + col] = __float2bfloat16(v0);
                C[(size_t)(rb1 + r) * NN + col] = __float2bfloat16(v1);
            }
        } else {
#pragma unroll
            for (int r = 0; r < 4; ++r) {
                C[(size_t)(rb0 + r) * NN + col] = __float2bfloat16(acc0[r] * sc0[r]);
                C[(size_t)(rb1 + r) * NN + col] = __float2bfloat16(acc1[r] * sc1[r]);
            }
        }
    }
}

// ---------------- aggregation 2 (grouped gather) ----------------

__global__ __launch_bounds__(256) void k_agg2(
        const s16x8* __restrict__ h8, const int* __restrict__ offsets,
        const int* __restrict__ csr, const float* __restrict__ dinv,
        const __hip_bfloat16* __restrict__ b2c, const int* __restrict__ flags,
        void* __restrict__ outraw, int N, int nwaves) {
    int gw   = blockIdx.x * 4 + (threadIdx.x >> 6);
    int lane = threadIdx.x & 63;
    int g = lane >> 4, li = lane & 15;
    int f32 = flags[0];
    float bb[8];
    {
        s16x8 bv = ((const s16x8*)b2c)[li];
        __hip_bfloat162* bp = (__hip_bfloat162*)&bv;
#pragma unroll
        for (int j = 0; j < 4; ++j) {
            float2 f = bf2f(bp[j]);
            bb[2 * j] = f.x; bb[2 * j + 1] = f.y;
        }
    }
    for (int v = gw; v < N; v += nwaves) {
        float acc[8];
#pragma unroll
        for (int j = 0; j < 8; ++j) acc[j] = 0.f;
        int o0 = offsets[v], o1 = offsets[v + 1];
        if (g == 0) acc_row(acc, h8[(size_t)v * 16 + li]);    // self (pre-scaled)
        int e = o0 + g;
        for (; e + 4 < o1; e += 8) {
            int s0 = csr[e], s1 = csr[e + 4];
            s16x8 r0 = h8[(size_t)s0 * 16 + li];
            s16x8 r1 = h8[(size_t)s1 * 16 + li];
            acc_row(acc, r0);
            acc_row(acc, r1);
        }
        if (e < o1) acc_row(acc, h8[(size_t)csr[e] * 16 + li]);
#pragma unroll
        for (int j = 0; j < 8; ++j) {
            acc[j] += __shfl_xor(acc[j], 16, 64);
            acc[j] += __shfl_xor(acc[j], 32, 64);
        }
        if (g == 0) {
            float dv = dinv[v];
            if (f32) {
                float4* of = (float4*)outraw;
                float4 o0v = {dv * acc[0] + bb[0], dv * acc[1] + bb[1],
                              dv * acc[2] + bb[2], dv * acc[3] + bb[3]};
                float4 o1v = {dv * acc[4] + bb[4], dv * acc[5] + bb[5],
                              dv * acc[6] + bb[6], dv * acc[7] + bb[7]};
                of[(size_t)v * 32 + li * 2]     = o0v;
                of[(size_t)v * 32 + li * 2 + 1] = o1v;
            } else {
                s16x8 outv;
                __hip_bfloat162* op = (__hip_bfloat162*)&outv;
#pragma unroll
                for (int j = 0; j < 4; ++j)
                    op[j] = f2bf(dv * acc[2 * j] + bb[2 * j], dv * acc[2 * j + 1] + bb[2 * j + 1]);
                ((s16x8*)outraw)[(size_t)v * 16 + li] = outv;
            }
        }
    }
}

// ---------------- host launch ----------------

extern "C" void kernel_launch(void* const* d_in, const int* in_sizes, int n_in,
                              void* d_out, int out_size, void* d_ws, size_t ws_size,
                              hipStream_t stream) {
    const void* x  = d_in[0];
    const void* ei = d_in[1];
    const void* W1 = d_in[2];
    const void* b1 = d_in[3];
    const void* W2 = d_in[4];
    const void* b2 = d_in[5];

    const int N = in_sizes[0] / IN_DIM;       // 50000
    const int E = in_sizes[1] / 2;            // 800000
    const int Npad = ((N + 127) / 128) * 128; // 50048 (multiple of 128)
    const int NB = (N + BKT_NODES - 1) / BKT_NODES;   // 391 (NB*128 == Npad)

    char* w = (char*)d_ws;
    auto alloc = [&](size_t bytes) -> void* {
        void* p = (void*)w;
        w += (bytes + 255) / 256 * 256;
        return p;
    };
    int*   flags   = (int*)alloc(256);
    int*   bcnt    = (int*)alloc((size_t)MAXB * 4);
    int*   boff    = (int*)alloc((size_t)(MAXB + 1) * 4);
    int*   offsets = (int*)alloc((size_t)(N + 1) * 4);
    float* dinv    = (float*)alloc((size_t)Npad * 4);
    unsigned* ppack = (unsigned*)alloc((size_t)NB * CAP * 4);
    int*   csr     = (int*)alloc((size_t)E * 4);
    short* Bsw1 = (short*)alloc((size_t)IN_DIM * HID * 2);
    short* Bsw2 = (short*)alloc((size_t)HID * OUTD * 2);
    __hip_bfloat16* b1c = (__hip_bfloat16*)alloc((size_t)HID * 2);
    __hip_bfloat16* b2c = (__hip_bfloat16*)alloc((size_t)OUTD * 2);
    __hip_bfloat16* xs  = (__hip_bfloat16*)alloc((size_t)Npad * IN_DIM * 2);
    __hip_bfloat16* a1  = (__hip_bfloat16*)alloc((size_t)Npad * IN_DIM * 2);
    __hip_bfloat16* h1  = (__hip_bfloat16*)alloc((size_t)Npad * HID * 2);
    __hip_bfloat16* h2s = xs;   // xs dead after agg1; reuse for GEMM2 output

    k_detect<<<1, 64, 0, stream>>>(W2, ei, flags);
    hipMemsetAsync(bcnt, 0, (size_t)MAXB * 4, stream);

    k_prep_w<<<33, 256, 0, stream>>>(W1, b1, W2, b2, flags, Bsw1, Bsw2, b1c, b2c);

    k_edges<<<EBLK, 256, 0, stream>>>(ei, E, N, NB, flags, bcnt, ppack);
    k_bscan<<<1, MAXB, 0, stream>>>(bcnt, NB, boff, offsets, dinv, N, Npad);
    k_bsort<<<NB, 256, 0, stream>>>(boff, bcnt, ppack, csr, offsets, dinv, N,
                                    x, flags, xs);

    const int aggBlocks = 2048, nwaves = aggBlocks * 4;
    k_agg1<<<aggBlocks, 256, 0, stream>>>((const s16x8*)xs, offsets, csr, dinv,
                                          (s16x8*)a1, N, Npad, nwaves);

    k_gemm<IN_DIM, HID, true><<<Npad / 128, 256, 0, stream>>>(
        a1, (const __hip_bfloat16*)Bsw1, b1c, nullptr, h1);
    k_gemm<HID, OUTD, false><<<Npad / 128, 256, 0, stream>>>(
        h1, (const __hip_bfloat16*)Bsw2, nullptr, dinv, h2s);

    k_agg2<<<aggBlocks, 256, 0, stream>>>((const s16x8*)h2s, offsets, csr, dinv,
                                          b2c, flags, d_out, N, nwaves);
}

// Round 8
// 220.114 us; speedup vs baseline: 4.8290x; 1.0187x over previous
//
#include <hip/hip_runtime.h>
#include <hip/hip_bf16.h>

// GCN 2-layer encoder, MI355X (gfx950).
// Known: float tensors bf16, edge_index int64 (self-detection kept).
// Round 8: consolidation — k_detect deleted (prep_w self-detects, writes
// flags), k_bscan folded into k_bsort (512-thr block-local scan), both GEMMs
// fused (h1 in XOR-swizzled LDS, per-wave-private, no barrier), aggs
// unroll-4. 7 dispatches.
// Pipeline:
//   k_prep_w: Bsw1/Bsw2 (MFMA B-frag order) + b1c/b2c + flags
//   k_edges -> k_bsort(+scan +prescale xs=dinv*x): CSR/offsets/dinv/xs
//   a1[v] = dinv[v]*(xs[v] + sum xs[csr])      [gather, grouped]
//   h2s = (relu(a1@W1+b1) @ W2) * dinv[row]     [fused MFMA, LDS h1]
//   out[v] = dinv[v]*(h2s[v] + sum h2s[csr]) + b2   [gather, grouped]

typedef __bf16 bf16x8v __attribute__((ext_vector_type(8)));
typedef short  s16x8   __attribute__((ext_vector_type(8)));
typedef float  f32x4   __attribute__((ext_vector_type(4)));

#define IN_DIM 128
#define HID    256
#define OUTD   128
#define BKT_SHIFT 7
#define BKT_NODES 128
#define MAXB 512            // max buckets (N <= 65536)
#define CAP  8192           // per-bucket capacity (mean 2046, 40+ sigma margin)
#define EBLK 512            // k_edges grid

__device__ __forceinline__ float2 bf2f(__hip_bfloat162 v) {
    return make_float2(__bfloat162float(v.x), __bfloat162float(v.y));
}
__device__ __forceinline__ __hip_bfloat162 f2bf(float a, float b) {
    __hip_bfloat162 r; r.x = __float2bfloat16(a); r.y = __float2bfloat16(b); return r;
}
__device__ __forceinline__ void acc_row(float* acc, s16x8 r) {
    __hip_bfloat162* p = (__hip_bfloat162*)&r;
#pragma unroll
    for (int j = 0; j < 4; ++j) {
        float2 f = bf2f(p[j]);
        acc[2 * j]     += f.x;
        acc[2 * j + 1] += f.y;
    }
}

// per-block dtype self-detection (W2 uniform +-1/16: any bf16-exp >= 0x7F => fp32)
__device__ __forceinline__ int detect_f32(const void* W2raw) {
    const unsigned short* u = (const unsigned short*)W2raw;
    int f32 = 0;
#pragma unroll
    for (int i = 0; i < 64; ++i) {
        unsigned e = (u[i] >> 7) & 0xFF;
        if (e >= 0x7F) f32 = 1;
    }
    return f32;
}

// ---------------- fused weight prep (+flags) ----------------
// Bsw[(nt*KC+kc)*64 + lane][j] = W[kc*32 + (lane>>4)*8 + j][nt*16 + (lane&15)]

__device__ __forceinline__ short ldw(const void* raw, int idx, int f32) {
    if (f32) {
        __hip_bfloat16 h = __float2bfloat16(((const float*)raw)[idx]);
        return *(short*)&h;
    }
    return ((const short*)raw)[idx];
}

template <int K, int NN>
__device__ __forceinline__ void swz_one(const void* Wraw, int f32,
                                        short* __restrict__ Bsw, int tid) {
    constexpr int KC = K / 32;
    constexpr int NT = NN / 16;
    if (tid >= NT * KC * 64) return;
    int lane = tid & 63;
    int kc   = (tid >> 6) % KC;
    int nt   = tid / (64 * KC);
    int n  = nt * 16 + (lane & 15);
    int kb = kc * 32 + (lane >> 4) * 8;
    s16x8 v;
#pragma unroll
    for (int j = 0; j < 8; ++j) v[j] = ldw(Wraw, (kb + j) * NN + n, f32);
    ((s16x8*)Bsw)[tid] = v;
}

__global__ __launch_bounds__(256) void k_prep_w(
        const void* W1raw, const void* b1raw, const void* W2raw, const void* b2raw,
        const void* eiraw, short* __restrict__ Bsw1, short* __restrict__ Bsw2,
        __hip_bfloat16* __restrict__ b1c, __hip_bfloat16* __restrict__ b2c,
        int* __restrict__ flags) {
    int f32 = detect_f32(W2raw);
    int blk = blockIdx.x, t = threadIdx.x;
    if (blk < 16) {
        swz_one<IN_DIM, HID>(W1raw, f32, Bsw1, blk * 256 + t);
    } else if (blk < 32) {
        swz_one<HID, OUTD>(W2raw, f32, Bsw2, (blk - 16) * 256 + t);
    } else {
        short s1 = ldw(b1raw, t, f32);
        b1c[t] = *(__hip_bfloat16*)&s1;
        if (t < OUTD) {
            short s2 = ldw(b2raw, t, f32);
            b2c[t] = *(__hip_bfloat16*)&s2;
        }
        if (t == 0) {
            const unsigned* ip = (const unsigned*)eiraw;
            unsigned orodd = 0;
#pragma unroll
            for (int i = 0; i < 64; ++i) orodd |= ip[2 * i + 1];
            flags[0] = f32;
            flags[1] = (orodd == 0) ? 1 : 0;   // int64 upper words all zero
        }
    }
}

// ---------------- one-pass edge bucketing (wave-privatized) ----------------

__global__ __launch_bounds__(256) void k_edges(
        const void* __restrict__ ei_, int E, int N, int NB,
        const int* __restrict__ flags, int* __restrict__ bcnt,
        unsigned* __restrict__ ppack) {
    __shared__ int lhist[4][MAXB];
    __shared__ int lbase[4][MAXB];
    int wv = threadIdx.x >> 6;
    int i64 = flags[1];
    const long long* p64 = (const long long*)ei_;
    const int*       p32 = (const int*)ei_;
    int per = (E + gridDim.x - 1) / gridDim.x;
    int e0 = blockIdx.x * per, e1 = min(e0 + per, E);
    for (int i = threadIdx.x; i < NB; i += 256) {
        lhist[0][i] = 0; lhist[1][i] = 0; lhist[2][i] = 0; lhist[3][i] = 0;
    }
    __syncthreads();
    for (int e = e0 + threadIdx.x; e < e1; e += 256) {
        int d = i64 ? (int)p64[E + e] : p32[E + e];
        if ((unsigned)d >= (unsigned)N) d = 0;
        atomicAdd(&lhist[wv][((unsigned)d) >> BKT_SHIFT], 1);
    }
    __syncthreads();
    for (int i = threadIdx.x; i < NB; i += 256) {
        int c0 = lhist[0][i], c1 = lhist[1][i], c2 = lhist[2][i], c3 = lhist[3][i];
        int tot = c0 + c1 + c2 + c3;
        int g = tot ? atomicAdd(&bcnt[i], tot) : 0;
        lbase[0][i] = g;
        lbase[1][i] = g + c0;
        lbase[2][i] = g + c0 + c1;
        lbase[3][i] = g + c0 + c1 + c2;
        lhist[0][i] = 0; lhist[1][i] = 0; lhist[2][i] = 0; lhist[3][i] = 0;
    }
    __syncthreads();
    for (int e = e0 + threadIdx.x; e < e1; e += 256) {
        int d = i64 ? (int)p64[E + e] : p32[E + e];
        int s = i64 ? (int)p64[e]     : p32[e];
        if ((unsigned)d >= (unsigned)N) d = 0;
        if ((unsigned)s >= (unsigned)N) s = 0;
        int b = ((unsigned)d) >> BKT_SHIFT;
        int pos = lbase[wv][b] + atomicAdd(&lhist[wv][b], 1);
        if (pos < CAP)
            ppack[(size_t)b * CAP + pos] = ((unsigned)(d & (BKT_NODES - 1)) << 25) | (unsigned)s;
    }
}

// ---------------- bucket sort (+bucket scan, +prescale xs) ----------------
// one 512-thr block per bucket: local scan of bcnt -> ebase; counting-sort by
// local dst -> csr (coalesced window); offsets + dinv; xs = dinv*x for its rows.

__global__ __launch_bounds__(512) void k_bsort(const int* __restrict__ bcnt,
                                               const unsigned* __restrict__ ppack,
                                               int NB,
                                               int* __restrict__ csr, int* __restrict__ offsets,
                                               float* __restrict__ dinv, int N,
                                               const void* __restrict__ xraw,
                                               const int* __restrict__ flags,
                                               __hip_bfloat16* __restrict__ xs) {
    __shared__ int sb[MAXB];
    __shared__ int h[BKT_NODES], base[BKT_NODES], s[BKT_NODES];
    __shared__ float sdv[BKT_NODES];
    int b = blockIdx.x;
    int t = threadIdx.x;
    // block-local exclusive scan of clamped bcnt
    int c = (t < NB) ? min(bcnt[t], CAP) : 0;
    sb[t] = c;
    __syncthreads();
    for (int off = 1; off < MAXB; off <<= 1) {
        int u = (t >= off) ? sb[t - off] : 0;
        __syncthreads();
        sb[t] += u;
        __syncthreads();
    }
    int cnt   = min(bcnt[b], CAP);
    int ebase = sb[b] - cnt;
    if (b == NB - 1 && t == 0) offsets[N] = sb[b];   // total edges kept
    const unsigned* pp = ppack + (size_t)b * CAP;
    if (t < BKT_NODES) h[t] = 0;
    __syncthreads();
    for (int e = t; e < cnt; e += 512) atomicAdd(&h[pp[e] >> 25], 1);
    __syncthreads();
    int v = (t < BKT_NODES) ? h[t] : 0;
    if (t < BKT_NODES) s[t] = v;
    __syncthreads();
    for (int off = 1; off < BKT_NODES; off <<= 1) {
        int u = (t < BKT_NODES && t >= off) ? s[t - off] : 0;
        __syncthreads();
        if (t < BKT_NODES) s[t] += u;
        __syncthreads();
    }
    if (t < BKT_NODES) {
        int excl = s[t] - v;
        base[t] = excl;
        int node = b * BKT_NODES + t;
        float dv = 0.f;
        if (node < N) {
            dv = rsqrtf((float)(v + 1));
            offsets[node] = ebase + excl;
            dinv[node] = dv;
        } else {
            dinv[node] = 0.f;
        }
        sdv[t] = dv;
        h[t] = 0;   // reuse as cursor
    }
    __syncthreads();
    for (int e = t; e < cnt; e += 512) {
        unsigned pk = pp[e];
        int ld = pk >> 25;
        int pos = ebase + base[ld] + atomicAdd(&h[ld], 1);
        csr[pos] = (int)(pk & 0x1FFFFFFu);
    }
    // fused prescale: xs rows [b*128, b*128+128) = dinv * x
    int f32 = flags[0];
    if (!f32) {
        const s16x8* xg = (const s16x8*)xraw;           // 16 units of 8 bf16 per row
        s16x8* xo = (s16x8*)xs;
        for (int u = t; u < BKT_NODES * 16; u += 512) {
            int row = u >> 4;
            int node = b * BKT_NODES + row;
            float dv = sdv[row];
            s16x8 val = {0, 0, 0, 0, 0, 0, 0, 0};
            if (node < N) {
                s16x8 xin = xg[(size_t)node * 16 + (u & 15)];
                __hip_bfloat162* xp = (__hip_bfloat162*)&xin;
                __hip_bfloat162* vp = (__hip_bfloat162*)&val;
#pragma unroll
                for (int j = 0; j < 4; ++j) {
                    float2 f = bf2f(xp[j]);
                    vp[j] = f2bf(dv * f.x, dv * f.y);
                }
            }
            xo[(size_t)node * 16 + (u & 15)] = val;
        }
    } else {
        const float4* xg = (const float4*)xraw;         // 32 units of 4 f32 per row
        __hip_bfloat162* xo = (__hip_bfloat162*)xs;
        for (int u = t; u < BKT_NODES * 32; u += 512) {
            int row = u >> 5;
            int node = b * BKT_NODES + row;
            float dv = sdv[row];
            __hip_bfloat162 v0 = f2bf(0.f, 0.f), v1 = v0;
            if (node < N) {
                float4 xin = xg[(size_t)node * 32 + (u & 31)];
                v0 = f2bf(dv * xin.x, dv * xin.y);
                v1 = f2bf(dv * xin.z, dv * xin.w);
            }
            xo[(size_t)node * 64 + (u & 31) * 2]     = v0;
            xo[(size_t)node * 64 + (u & 31) * 2 + 1] = v1;
        }
    }
}

// ---------------- aggregation 1 (grouped gather, unroll 4) ----------------
// 16 lanes per row (16B/lane), 4 edge-groups per wave, shfl_xor combine.

__global__ __launch_bounds__(256) void k_agg1(
        const s16x8* __restrict__ xs8, const int* __restrict__ offsets,
        const int* __restrict__ csr, const float* __restrict__ dinv,
        s16x8* __restrict__ a8, int N, int Npad, int nwaves) {
    int gw   = blockIdx.x * 4 + (threadIdx.x >> 6);
    int lane = threadIdx.x & 63;
    int g = lane >> 4, li = lane & 15;
    for (int v = gw; v < Npad; v += nwaves) {
        if (v >= N) {
            if (g == 0) { s16x8 z = {0,0,0,0,0,0,0,0}; a8[(size_t)v * 16 + li] = z; }
            continue;
        }
        float acc[8];
#pragma unroll
        for (int j = 0; j < 8; ++j) acc[j] = 0.f;
        int o0 = offsets[v], o1 = offsets[v + 1];
        if (g == 0) acc_row(acc, xs8[(size_t)v * 16 + li]);   // self (pre-scaled)
        int e = o0 + g;
        for (; e + 12 < o1; e += 16) {
            int s0 = csr[e], s1 = csr[e + 4], s2 = csr[e + 8], s3 = csr[e + 12];
            s16x8 r0 = xs8[(size_t)s0 * 16 + li];
            s16x8 r1 = xs8[(size_t)s1 * 16 + li];
            s16x8 r2 = xs8[(size_t)s2 * 16 + li];
            s16x8 r3 = xs8[(size_t)s3 * 16 + li];
            acc_row(acc, r0); acc_row(acc, r1); acc_row(acc, r2); acc_row(acc, r3);
        }
        for (; e < o1; e += 4) acc_row(acc, xs8[(size_t)csr[e] * 16 + li]);
#pragma unroll
        for (int j = 0; j < 8; ++j) {
            acc[j] += __shfl_xor(acc[j], 16, 64);
            acc[j] += __shfl_xor(acc[j], 32, 64);
        }
        if (g == 0) {
            float dv = dinv[v];
            s16x8 outv;
            __hip_bfloat162* op = (__hip_bfloat162*)&outv;
#pragma unroll
            for (int j = 0; j < 4; ++j) op[j] = f2bf(dv * acc[2 * j], dv * acc[2 * j + 1]);
            a8[(size_t)v * 16 + li] = outv;
        }
    }
}

// ---------------- fused MFMA GEMM1+GEMM2 ----------------
// Block = 4 waves, 128 rows/tile, wave owns 32 rows. Phase 1: h1 = relu(A@W1+b1)
// into XOR-swizzled LDS (per-wave-private rows -> no barrier). Phase 2:
// h2s = (h1@W2)*dinv. LDS granule swizzle: g = gcol ^ (row&31), 16B granules.

__global__ __launch_bounds__(256) void k_gemm12(
        const __hip_bfloat16* __restrict__ A, const __hip_bfloat16* __restrict__ Bsw1,
        const __hip_bfloat16* __restrict__ b1c, const __hip_bfloat16* __restrict__ Bsw2,
        const float* __restrict__ dinv, __hip_bfloat16* __restrict__ h2s) {
    __shared__ __align__(16) __hip_bfloat16 hl[128 * HID];   // 64 KB
    int wave = threadIdx.x >> 6, lane = threadIdx.x & 63;
    int quad = lane >> 4, l16 = lane & 15;
    int mw = wave * 32;                    // wave row base in tile
    int gm = blockIdx.x * 128 + mw;        // global row base

    // phase 1
    bf16x8v a1f[2][4];
#pragma unroll
    for (int st = 0; st < 2; ++st)
#pragma unroll
        for (int kc = 0; kc < 4; ++kc)
            a1f[st][kc] = *reinterpret_cast<const bf16x8v*>(
                A + (size_t)(gm + st * 16 + l16) * IN_DIM + kc * 32 + quad * 8);

    const bf16x8v* B1 = reinterpret_cast<const bf16x8v*>(Bsw1);
    for (int nt = 0; nt < HID / 16; ++nt) {
        f32x4 acc0 = {0.f, 0.f, 0.f, 0.f}, acc1 = {0.f, 0.f, 0.f, 0.f};
#pragma unroll
        for (int kc = 0; kc < 4; ++kc) {
            bf16x8v bfrag = B1[(nt * 4 + kc) * 64 + lane];
            acc0 = __builtin_amdgcn_mfma_f32_16x16x32_bf16(a1f[0][kc], bfrag, acc0, 0, 0, 0);
            acc1 = __builtin_amdgcn_mfma_f32_16x16x32_bf16(a1f[1][kc], bfrag, acc1, 0, 0, 0);
        }
        int col = nt * 16 + l16;
        int gcol = col >> 3, csub = col & 7;
        float bv = __bfloat162float(b1c[col]);
#pragma unroll
        for (int r = 0; r < 4; ++r) {
            float v0 = acc0[r] + bv; v0 = v0 > 0.f ? v0 : 0.f;
            float v1 = acc1[r] + bv; v1 = v1 > 0.f ? v1 : 0.f;
            int r0 = mw + quad * 4 + r;
            int r1 = mw + 16 + quad * 4 + r;
            ((__hip_bfloat16*)((char*)hl + (size_t)r0 * (HID * 2) + ((gcol ^ (r0 & 31)) << 4)))[csub] = __float2bfloat16(v0);
            ((__hip_bfloat16*)((char*)hl + (size_t)r1 * (HID * 2) + ((gcol ^ (r1 & 31)) << 4)))[csub] = __float2bfloat16(v1);
        }
    }
    // per-wave-private rows: no __syncthreads needed (same wave wrote them)

    // phase 2
    bf16x8v a2f[2][8];
#pragma unroll
    for (int st = 0; st < 2; ++st)
#pragma unroll
        for (int kc = 0; kc < 8; ++kc) {
            int row = mw + st * 16 + l16;
            int g = (kc * 4 + quad) ^ (row & 31);
            a2f[st][kc] = *reinterpret_cast<const bf16x8v*>(
                (char*)hl + (size_t)row * (HID * 2) + ((size_t)g << 4));
        }
    const bf16x8v* B2 = reinterpret_cast<const bf16x8v*>(Bsw2);
    int rb0 = gm + quad * 4, rb1 = gm + 16 + quad * 4;
    float sc0[4], sc1[4];
#pragma unroll
    for (int r = 0; r < 4; ++r) { sc0[r] = dinv[rb0 + r]; sc1[r] = dinv[rb1 + r]; }
    for (int nt = 0; nt < OUTD / 16; ++nt) {
        f32x4 acc0 = {0.f, 0.f, 0.f, 0.f}, acc1 = {0.f, 0.f, 0.f, 0.f};
#pragma unroll
        for (int kc = 0; kc < 8; ++kc) {
            bf16x8v bfrag = B2[(nt * 8 + kc) * 64 + lane];
            acc0 = __builtin_amdgcn_mfma_f32_16x16x32_bf16(a2f[0][kc], bfrag, acc0, 0, 0, 0);
            acc1 = __builtin_amdgcn_mfma_f32_16x16x32_bf16(a2f[1][kc], bfrag, acc1, 0, 0, 0);
        }
        int col = nt * 16 + l16;
#pragma unroll
        for (int r = 0; r < 4; ++r) {
            h2s[(size_t)(rb0 + r) * OUTD + col] = __float2bfloat16(acc0[r] * sc0[r]);
            h2s[(size_t)(rb1 + r) * OUTD + col] = __float2bfloat16(acc1[r] * sc1[r]);
        }
    }
}

// ---------------- aggregation 2 (grouped gather, unroll 4) ----------------

__global__ __launch_bounds__(256) void k_agg2(
        const s16x8* __restrict__ h8, const int* __restrict__ offsets,
        const int* __restrict__ csr, const float* __restrict__ dinv,
        const __hip_bfloat16* __restrict__ b2c, const int* __restrict__ flags,
        void* __restrict__ outraw, int N, int nwaves) {
    int gw   = blockIdx.x * 4 + (threadIdx.x >> 6);
    int lane = threadIdx.x & 63;
    int g = lane >> 4, li = lane & 15;
    int f32 = flags[0];
    float bb[8];
    {
        s16x8 bv = ((const s16x8*)b2c)[li];
        __hip_bfloat162* bp = (__hip_bfloat162*)&bv;
#pragma unroll
        for (int j = 0; j < 4; ++j) {
            float2 f = bf2f(bp[j]);
            bb[2 * j] = f.x; bb[2 * j + 1] = f.y;
        }
    }
    for (int v = gw; v < N; v += nwaves) {
        float acc[8];
#pragma unroll
        for (int j = 0; j < 8; ++j) acc[j] = 0.f;
        int o0 = offsets[v], o1 = offsets[v + 1];
        if (g == 0) acc_row(acc, h8[(size_t)v * 16 + li]);    // self (pre-scaled)
        int e = o0 + g;
        for (; e + 12 < o1; e += 16) {
            int s0 = csr[e], s1 = csr[e + 4], s2 = csr[e + 8], s3 = csr[e + 12];
            s16x8 r0 = h8[(size_t)s0 * 16 + li];
            s16x8 r1 = h8[(size_t)s1 * 16 + li];
            s16x8 r2 = h8[(size_t)s2 * 16 + li];
            s16x8 r3 = h8[(size_t)s3 * 16 + li];
            acc_row(acc, r0); acc_row(acc, r1); acc_row(acc, r2); acc_row(acc, r3);
        }
        for (; e < o1; e += 4) acc_row(acc, h8[(size_t)csr[e] * 16 + li]);
#pragma unroll
        for (int j = 0; j < 8; ++j) {
            acc[j] += __shfl_xor(acc[j], 16, 64);
            acc[j] += __shfl_xor(acc[j], 32, 64);
        }
        if (g == 0) {
            float dv = dinv[v];
            if (f32) {
                float4* of = (float4*)outraw;
                float4 o0v = {dv * acc[0] + bb[0], dv * acc[1] + bb[1],
                              dv * acc[2] + bb[2], dv * acc[3] + bb[3]};
                float4 o1v = {dv * acc[4] + bb[4], dv * acc[5] + bb[5],
                              dv * acc[6] + bb[6], dv * acc[7] + bb[7]};
                of[(size_t)v * 32 + li * 2]     = o0v;
                of[(size_t)v * 32 + li * 2 + 1] = o1v;
            } else {
                s16x8 outv;
                __hip_bfloat162* op = (__hip_bfloat162*)&outv;
#pragma unroll
                for (int j = 0; j < 4; ++j)
                    op[j] = f2bf(dv * acc[2 * j] + bb[2 * j], dv * acc[2 * j + 1] + bb[2 * j + 1]);
                ((s16x8*)outraw)[(size_t)v * 16 + li] = outv;
            }
        }
    }
}

// ---------------- host launch ----------------

extern "C" void kernel_launch(void* const* d_in, const int* in_sizes, int n_in,
                              void* d_out, int out_size, void* d_ws, size_t ws_size,
                              hipStream_t stream) {
    const void* x  = d_in[0];
    const void* ei = d_in[1];
    const void* W1 = d_in[2];
    const void* b1 = d_in[3];
    const void* W2 = d_in[4];
    const void* b2 = d_in[5];

    const int N = in_sizes[0] / IN_DIM;       // 50000
    const int E = in_sizes[1] / 2;            // 800000
    const int Npad = ((N + 127) / 128) * 128; // 50048 (multiple of 128)
    const int NB = Npad / BKT_NODES;          // 391

    char* w = (char*)d_ws;
    auto alloc = [&](size_t bytes) -> void* {
        void* p = (void*)w;
        w += (bytes + 255) / 256 * 256;
        return p;
    };
    int*   flags   = (int*)alloc(256);
    int*   bcnt    = (int*)alloc((size_t)MAXB * 4);
    int*   offsets = (int*)alloc((size_t)(N + 1) * 4);
    float* dinv    = (float*)alloc((size_t)Npad * 4);
    unsigned* ppack = (unsigned*)alloc((size_t)NB * CAP * 4);
    int*   csr     = (int*)alloc((size_t)E * 4);
    short* Bsw1 = (short*)alloc((size_t)IN_DIM * HID * 2);
    short* Bsw2 = (short*)alloc((size_t)HID * OUTD * 2);
    __hip_bfloat16* b1c = (__hip_bfloat16*)alloc((size_t)HID * 2);
    __hip_bfloat16* b2c = (__hip_bfloat16*)alloc((size_t)OUTD * 2);
    __hip_bfloat16* xs  = (__hip_bfloat16*)alloc((size_t)Npad * IN_DIM * 2);
    __hip_bfloat16* a1  = (__hip_bfloat16*)alloc((size_t)Npad * IN_DIM * 2);
    __hip_bfloat16* h2s = xs;   // xs dead after agg1; reuse for gemm12 output

    k_prep_w<<<33, 256, 0, stream>>>(W1, b1, W2, b2, ei, Bsw1, Bsw2, b1c, b2c, flags);
    hipMemsetAsync(bcnt, 0, (size_t)MAXB * 4, stream);

    k_edges<<<EBLK, 256, 0, stream>>>(ei, E, N, NB, flags, bcnt, ppack);
    k_bsort<<<NB, 512, 0, stream>>>(bcnt, ppack, NB, csr, offsets, dinv, N,
                                    x, flags, xs);

    const int aggBlocks = 2048, nwaves = aggBlocks * 4;
    k_agg1<<<aggBlocks, 256, 0, stream>>>((const s16x8*)xs, offsets, csr, dinv,
                                          (s16x8*)a1, N, Npad, nwaves);

    k_gemm12<<<NB, 256, 0, stream>>>(a1, (const __hip_bfloat16*)Bsw1, b1c,
                                     (const __hip_bfloat16*)Bsw2, dinv, h2s);

    k_agg2<<<aggBlocks, 256, 0, stream>>>((const s16x8*)h2s, offsets, csr, dinv,
                                          b2c, flags, d_out, N, nwaves);
}